// Round 5
// baseline (3090.337 us; speedup 1.0000x reference)
//
#include <hip/hip_runtime.h>
#include <hip/hip_bf16.h>

#define DD 128
#define BN_EPS 1e-5f

typedef __hip_bfloat16 bf16;

__device__ __forceinline__ float b2f(unsigned short u) {
    union { float f; unsigned int i; } x; x.i = ((unsigned int)u) << 16; return x.f;
}

// ---- dtype detect: flag=1 if d_in[0] is packed bf16, 0 if f32 ----
// For a 32-bit word, bits [14:7] are the LOW half's bf16 exponent field.
// bf16 N(0,1) data: exponent in [90,140] essentially always. f32 data:
// those bits are mid-mantissa, uniform -> ~20% in-band. 256 samples, thresh 128.
__global__ void detect_dtype(const unsigned int* __restrict__ x, int* __restrict__ flag) {
    __shared__ int s[256];
    int t = threadIdx.x;
    unsigned int u = x[t];
    unsigned int e = (u >> 7) & 0xFFu;
    s[t] = ((e >= 90u && e <= 140u) || ((u & 0xFFFFu) == 0u)) ? 1 : 0;
    __syncthreads();
    for (int off = 128; off > 0; off >>= 1) { if (t < off) s[t] += s[t + off]; __syncthreads(); }
    if (t == 0) *flag = (s[0] >= 128) ? 1 : 0;
}

// ---- convert one tensor (bf16 or f32 per flag) to f32 in ws ----
__global__ __launch_bounds__(256) void cvt(const void* __restrict__ src, float* __restrict__ dst,
                                           int n, const int* __restrict__ flagp) {
    int i = blockIdx.x * 256 + threadIdx.x;
    if (i >= n) return;
    if (*flagp) dst[i] = b2f(((const unsigned short*)src)[i]);
    else        dst[i] = ((const float*)src)[i];
}

// ---- per-layer in-degree histogram ----
__global__ __launch_bounds__(256) void deg_count(const int* __restrict__ dst, int nE,
                                                 float* __restrict__ deg) {
    int e = blockIdx.x * 256 + threadIdx.x;
    if (e < nE) atomicAdd(&deg[dst[e]], 1.0f);
}

// ---- edge scatter (segment sum) into dst window [lo,hi); flagp!=null => h may be bf16 ----
__global__ __launch_bounds__(256) void scatter_one(
    const void* __restrict__ hv, const int* __restrict__ flagp,
    const int* __restrict__ src, const int* __restrict__ dst,
    const int* __restrict__ gather, int nE, int lo, int hi,
    float* __restrict__ agg)
{
    int e = blockIdx.x * 2 + (threadIdx.x >> 7);
    int f = threadIdx.x & 127;
    if (e >= nE) return;
    int d = dst[e];
    if (d < lo || d >= hi) return;              // uniform across the 128-thread half-block
    int s = src[e];
    if (gather) s = gather[s];
    size_t idx = (size_t)s * DD + f;
    int abf = flagp ? *flagp : 0;
    float v = abf ? b2f(((const unsigned short*)hv)[idx]) : ((const float*)hv)[idx];
    atomicAdd(&agg[(size_t)(d - lo) * DD + f], v);
}

// ---- [M x 128] @ [128 x 128] GEMM, all f32; W staged in LDS in two K=64 halves ----
// flagp!=null => A may be bf16 (x). gather: row remap; degl: 1/max(deg,1) row scale.
__global__ __launch_bounds__(256) void gemm128(
    const void* __restrict__ Av, const int* __restrict__ flagp,
    const int* __restrict__ gather, const float* __restrict__ degl,
    const float* __restrict__ W, const float* __restrict__ bias,
    float* __restrict__ out, int M, int accum, int relu)
{
    __shared__ float As[32][129];
    __shared__ float Wsm[64 * DD];
    const int tid = threadIdx.x;
    const int rb = blockIdx.x * 32;
    const int abf = flagp ? *flagp : 0;

    { // stage A tile: 32 rows x 128
        int r = tid >> 3, c0 = (tid & 7) * 16;
        int gr = rb + r;
        if (gr < M) {
            int ar = gather ? gather[gr] : gr;
            float sc = degl ? 1.0f / fmaxf(degl[gr], 1.0f) : 1.0f;
            size_t base = (size_t)ar * DD + c0;
            if (abf) {
                const unsigned short* Ab = (const unsigned short*)Av;
#pragma unroll
                for (int j = 0; j < 16; ++j) As[r][c0 + j] = sc * b2f(Ab[base + j]);
            } else {
                const float* Af = (const float*)Av;
#pragma unroll
                for (int j = 0; j < 16; ++j) As[r][c0 + j] = sc * Af[base + j];
            }
        } else {
#pragma unroll
            for (int j = 0; j < 16; ++j) As[r][c0 + j] = 0.0f;
        }
    }

    const int tx = tid & 31, ty = tid >> 5;
    const int c = tx * 4;
    float acc[4][4] = {};

#pragma unroll
    for (int half = 0; half < 2; ++half) {
        __syncthreads();                         // A visible (h=0) / Wsm drained (h=1)
        { // stage W rows [half*64, half*64+64): 8192 floats via float4
            const float4* wsrc = (const float4*)(W + half * 64 * DD);
            float4* wdst = (float4*)Wsm;
#pragma unroll
            for (int i = 0; i < 8; ++i) wdst[i * 256 + tid] = wsrc[i * 256 + tid];
        }
        __syncthreads();
#pragma unroll 2
        for (int k2 = 0; k2 < 64; ++k2) {
            float4 wv = *(const float4*)&Wsm[k2 * DD + c];
            int k = half * 64 + k2;
            float a[4] = { As[ty][k], As[ty + 8][k], As[ty + 16][k], As[ty + 24][k] };
            float w[4] = { wv.x, wv.y, wv.z, wv.w };
#pragma unroll
            for (int i = 0; i < 4; ++i)
#pragma unroll
                for (int j = 0; j < 4; ++j) acc[i][j] = fmaf(a[i], w[j], acc[i][j]);
        }
    }

#pragma unroll
    for (int i = 0; i < 4; ++i) {
        int r = rb + ty + 8 * i;
        if (r >= M) continue;
        float* orow = out + (size_t)r * DD + c;
#pragma unroll
        for (int j = 0; j < 4; ++j) {
            float v = acc[i][j];
            if (bias) v += bias[c + j];
            if (accum) v += orow[j];
            if (relu) v = fmaxf(v, 0.0f);
            orow[j] = v;
        }
    }
}

// ---- per-column sum & sumsq ----
__global__ void colstats(const float* __restrict__ t, int M, int rowsPerBlock,
                         float* __restrict__ sum, float* __restrict__ sumsq) {
    int f = threadIdx.x;  // 128 threads
    int r0 = blockIdx.x * rowsPerBlock;
    int r1 = min(r0 + rowsPerBlock, M);
    float s = 0.0f, ss = 0.0f;
    for (int r = r0; r < r1; ++r) {
        float v = t[(size_t)r * DD + f];
        s += v; ss += v * v;
    }
    atomicAdd(&sum[f], s);
    atomicAdd(&sumsq[f], ss);
}

// ---- BN (population stats) + ReLU, in place ----
__global__ __launch_bounds__(256) void bn_relu(
    float* __restrict__ h, int M, const float* __restrict__ sum, const float* __restrict__ sumsq,
    const float* __restrict__ gamma, const float* __restrict__ beta) {
    size_t idx = (size_t)blockIdx.x * blockDim.x + threadIdx.x;
    if (idx >= (size_t)M * DD) return;
    int f = idx & 127;
    float m = sum[f] / (float)M;
    float v = fmaxf(sumsq[f] / (float)M - m * m, 0.0f);
    float inv = rsqrtf(v + BN_EPS);
    float xv = h[idx];
    h[idx] = fmaxf(gamma[f] * (xv - m) * inv + beta[f], 0.0f);
}

// ---- summary = sigmoid(colmean(P)); ws = disc_W @ summary ----
__global__ void make_ws(const float* __restrict__ colsum, const float* __restrict__ discW,
                        float* __restrict__ wsv, int M) {
    __shared__ float s[128];
    int t = threadIdx.x;  // 128 threads
    s[t] = 1.0f / (1.0f + expf(-(colsum[t] / (float)M)));
    __syncthreads();
    float acc = 0.0f;
    for (int j = 0; j < 128; ++j) acc += discW[t * 128 + j] * s[j];
    wsv[t] = acc;
}

// ---- discriminator loss ----
__global__ __launch_bounds__(256) void loss_kernel(
    const float* __restrict__ P, const float* __restrict__ Ng,
    const float* __restrict__ wsv, float* __restrict__ lsum, int M) {
    int row = blockIdx.x * 4 + (threadIdx.x >> 6);
    int lane = threadIdx.x & 63;
    if (row >= 2 * M) return;
    const float* base = (row < M) ? &P[(size_t)row * DD] : &Ng[(size_t)(row - M) * DD];
    float a = base[lane] * wsv[lane] + base[lane + 64] * wsv[lane + 64];
#pragma unroll
    for (int off = 32; off > 0; off >>= 1) a += __shfl_down(a, off, 64);
    if (lane == 0) {
        float x = (row < M) ? -a : a;
        float sp = fmaxf(x, 0.0f) + log1pf(expf(-fabsf(x)));
        atomicAdd(&lsum[row < M ? 0 : 1], sp);
    }
}

__global__ void write_loss(const float* __restrict__ lsum, void* __restrict__ outv, int M,
                           const int* __restrict__ flagp) {
    float v = (lsum[0] + lsum[1]) / (float)M;
    if (*flagp) ((bf16*)outv)[20000] = __float2bfloat16(v);
    else        ((float*)outv)[20000] = v;
}

// ---- predictor input: Z[i] = P[a]*P[b] for one pair list ----
__global__ __launch_bounds__(256) void pair_mult(
    const float* __restrict__ P, const int* __restrict__ s_idx, const int* __restrict__ d_idx,
    float* __restrict__ Z, int nPair) {
    int i = blockIdx.x * 2 + (threadIdx.x >> 7);
    int f = threadIdx.x & 127;
    if (i >= nPair) return;
    Z[(size_t)i * DD + f] = P[(size_t)s_idx[i] * DD + f] * P[(size_t)d_idx[i] * DD + f];
}

// ---- final 128 -> 1 matvec; store dtype per flag ----
__global__ __launch_bounds__(256) void final_mv(
    const float* __restrict__ ZB, const float* __restrict__ pW3, const float* __restrict__ pb3,
    void* __restrict__ outv, int nRows, int outOff, const int* __restrict__ flagp) {
    int row = blockIdx.x * 4 + (threadIdx.x >> 6);
    int lane = threadIdx.x & 63;
    if (row >= nRows) return;
    float a = ZB[(size_t)row * DD + lane] * pW3[lane]
            + ZB[(size_t)row * DD + lane + 64] * pW3[lane + 64];
#pragma unroll
    for (int off = 32; off > 0; off >>= 1) a += __shfl_down(a, off, 64);
    if (lane == 0) {
        float v = a + pb3[0];
        if (*flagp) ((bf16*)outv)[outOff + row] = __float2bfloat16(v);
        else        ((float*)outv)[outOff + row] = v;
    }
}

extern "C" void kernel_launch(void* const* d_in, const int* in_sizes, int n_in,
                              void* d_out, int out_size, void* d_ws, size_t ws_size,
                              hipStream_t stream)
{
    const void* x      = d_in[0];
    const int* srcA[3] = {(const int*)d_in[1], (const int*)d_in[3], (const int*)d_in[5]};
    const int* dstA[3] = {(const int*)d_in[2], (const int*)d_in[4], (const int*)d_in[6]};
    const int* perm    = (const int*)d_in[7];
    const int* pos_src = (const int*)d_in[8];
    const int* pos_dst = (const int*)d_in[9];
    const int* neg_src = (const int*)d_in[10];
    const int* neg_dst = (const int*)d_in[11];

    const int N1 = 50000, N2 = 25000, N3 = 12500;
    const int E[3] = {750000, 250000, 125000};
    const int EP = 10000;
    const int CH = 12500;

    // ---- ws layout (float offsets). Total 14,637,568 fl = 58.6 MiB ----
    float* wsf = (float*)d_ws;
    int*   flagp = (int*)d_ws;                    // [0]
    float* sumS   = wsf + 256;                    // 128
    float* sqS    = wsf + 384;                    // 128
    float* colsum = wsf + 512;                    // 128
    float* colsq  = wsf + 640;                    // 128
    float* wsvec  = wsf + 768;                    // 128
    float* lsum   = wsf + 896;                    // 2
    float* deg0   = wsf + 1024;                   // 50048
    float* deg1   = wsf + 51072;                  // 25024
    float* deg2   = wsf + 76096;                  // 12544
    const size_t WfB = 88704;                     // converted f32 weights
    float* WS[3] = {wsf + WfB +      0, wsf + WfB +  32896, wsf + WfB +  65792};
    float* WN[3] = {wsf + WfB +  16384, wsf + WfB +  49280, wsf + WfB +  82176};
    float* BV[3] = {wsf + WfB +  32768, wsf + WfB +  65664, wsf + WfB +  98560};
    float* G0 = wsf + WfB +  98688; float* BE0 = wsf + WfB +  98816;
    float* G1 = wsf + WfB +  98944; float* BE1 = wsf + WfB +  99072;
    float* DW  = wsf + WfB +  99200;
    float* PW1 = wsf + WfB + 115584; float* PB1 = wsf + WfB + 131968;
    float* PW2 = wsf + WfB + 132096; float* PB2 = wsf + WfB + 148480;
    float* PW3 = wsf + WfB + 148608; float* PB3 = wsf + WfB + 148736;
    float* PF  = wsf + 237568;                    // 1,600,000
    float* NF  = wsf + 1837568;                   // 1,600,000
    float* H2  = wsf + 3437568;                   // 3,200,000
    float* AGG = wsf + 6637568;                   // 1,600,000 (12500 rows)
    float* H1  = wsf + 8237568;                   // 6,400,000
    // predictor overlays inside dead AGG+H1 region:
    float* Z  = wsf + 6637568;
    float* ZA = wsf + 7917568;
    float* ZB = wsf + 9197568;

    // ---- dtype detect + weight conversion to f32 ----
    detect_dtype<<<1, 256, 0, stream>>>((const unsigned int*)x, flagp);
    struct CvtEnt { int idx; float* dst; int n; };
    const CvtEnt cvts[] = {
        {12, WS[0], 16384}, {13, WN[0], 16384}, {14, BV[0], 128},
        {15, WS[1], 16384}, {16, WN[1], 16384}, {17, BV[1], 128},
        {18, WS[2], 16384}, {19, WN[2], 16384}, {20, BV[2], 128},
        {21, G0, 128}, {22, BE0, 128}, {23, G1, 128}, {24, BE1, 128},
        {25, DW, 16384}, {26, PW1, 16384}, {27, PB1, 128},
        {28, PW2, 16384}, {29, PB2, 128}, {30, PW3, 128}, {31, PB3, 1},
    };
    for (auto& e : cvts)
        cvt<<<(e.n + 255) / 256, 256, 0, stream>>>(d_in[e.idx], e.dst, e.n, flagp);

    // ---- degrees (dst-only; shared by both passes) ----
    hipMemsetAsync(deg0, 0, (size_t)(50048 + 25024 + 12544) * 4, stream);
    deg_count<<<(E[0] + 255) / 256, 256, 0, stream>>>(dstA[0], E[0], deg0);
    deg_count<<<(E[1] + 255) / 256, 256, 0, stream>>>(dstA[1], E[1], deg1);
    deg_count<<<(E[2] + 255) / 256, 256, 0, stream>>>(dstA[2], E[2], deg2);

    const int gch = (CH + 31) / 32;

    for (int pass = 0; pass < 2; ++pass) {
        const int* g = (pass == 0) ? nullptr : perm;
        float* OUT = (pass == 0) ? PF : NF;

        // ===== layer 0 (M=50000): self, then 4 chunked neighbor accums =====
        gemm128<<<(N1 + 31) / 32, 256, 0, stream>>>(
            x, flagp, g, nullptr, WS[0], BV[0], H1, N1, 0, 0);
        for (int lo = 0; lo < N1; lo += CH) {
            hipMemsetAsync(AGG, 0, (size_t)CH * DD * 4, stream);
            scatter_one<<<(E[0] + 1) / 2, 256, 0, stream>>>(
                x, flagp, srcA[0], dstA[0], g, E[0], lo, lo + CH, AGG);
            gemm128<<<gch, 256, 0, stream>>>(
                AGG, nullptr, nullptr, deg0 + lo, WN[0], nullptr, H1 + (size_t)lo * DD, CH, 1, 0);
        }
        hipMemsetAsync(sumS, 0, 256 * 4, stream);
        colstats<<<(N1 + 255) / 256, 128, 0, stream>>>(H1, N1, 256, sumS, sqS);
        bn_relu<<<((size_t)N1 * DD + 255) / 256, 256, 0, stream>>>(H1, N1, sumS, sqS, G0, BE0);

        // ===== layer 1 (M=25000): 2 chunks =====
        gemm128<<<(N2 + 31) / 32, 256, 0, stream>>>(
            H1, nullptr, nullptr, nullptr, WS[1], BV[1], H2, N2, 0, 0);
        for (int lo = 0; lo < N2; lo += CH) {
            hipMemsetAsync(AGG, 0, (size_t)CH * DD * 4, stream);
            scatter_one<<<(E[1] + 1) / 2, 256, 0, stream>>>(
                H1, nullptr, srcA[1], dstA[1], nullptr, E[1], lo, lo + CH, AGG);
            gemm128<<<gch, 256, 0, stream>>>(
                AGG, nullptr, nullptr, deg1 + lo, WN[1], nullptr, H2 + (size_t)lo * DD, CH, 1, 0);
        }
        hipMemsetAsync(sumS, 0, 256 * 4, stream);
        colstats<<<(N2 + 255) / 256, 128, 0, stream>>>(H2, N2, 256, sumS, sqS);
        bn_relu<<<((size_t)N2 * DD + 255) / 256, 256, 0, stream>>>(H2, N2, sumS, sqS, G1, BE1);

        // ===== layer 2 (M=12500), no BN; 1 chunk =====
        gemm128<<<(N3 + 31) / 32, 256, 0, stream>>>(
            H2, nullptr, nullptr, nullptr, WS[2], BV[2], OUT, N3, 0, 0);
        hipMemsetAsync(AGG, 0, (size_t)N3 * DD * 4, stream);
        scatter_one<<<(E[2] + 1) / 2, 256, 0, stream>>>(
            H2, nullptr, srcA[2], dstA[2], nullptr, E[2], 0, N3, AGG);
        gemm128<<<gch, 256, 0, stream>>>(
            AGG, nullptr, nullptr, deg2, WN[2], nullptr, OUT, N3, 1, 0);
    }

    // ---- summary / discriminator loss ----
    hipMemsetAsync(colsum, 0, 256 * 4, stream);
    colstats<<<(N3 + 255) / 256, 128, 0, stream>>>(PF, N3, 256, colsum, colsq);
    make_ws<<<1, 128, 0, stream>>>(colsum, DW, wsvec, N3);
    hipMemsetAsync(lsum, 0, 2 * 4, stream);
    loss_kernel<<<(2 * N3) / 4, 256, 0, stream>>>(PF, NF, wsvec, lsum, N3);
    write_loss<<<1, 1, 0, stream>>>(lsum, d_out, N3, flagp);

    // ---- predictor MLP: chunk 0 = pos pairs, chunk 1 = neg pairs ----
    for (int c = 0; c < 2; ++c) {
        const int* si = (c == 0) ? pos_src : neg_src;
        const int* di = (c == 0) ? pos_dst : neg_dst;
        pair_mult<<<(EP + 1) / 2, 256, 0, stream>>>(PF, si, di, Z, EP);
        const int gp = (EP + 31) / 32;
        gemm128<<<gp, 256, 0, stream>>>(Z,  nullptr, nullptr, nullptr, PW1, PB1, ZA, EP, 0, 1);
        gemm128<<<gp, 256, 0, stream>>>(ZA, nullptr, nullptr, nullptr, PW2, PB2, ZB, EP, 0, 1);
        final_mv<<<(EP + 3) / 4, 256, 0, stream>>>(ZB, PW3, PB3, d_out, EP, c * EP, flagp);
    }
}

// Round 6
// 1980.757 us; speedup vs baseline: 1.5602x; 1.5602x over previous
//
#include <hip/hip_runtime.h>
#include <hip/hip_bf16.h>

#define DD 128
#define BN_EPS 1e-5f
#define NBLK 160   // blocks for stats/loss partial kernels

typedef __hip_bfloat16 bf16;

__device__ __forceinline__ float b2f(unsigned short u) {
    union { float f; unsigned int i; } x; x.i = ((unsigned int)u) << 16; return x.f;
}

// ---- dtype detect: flag=1 if d_in[0] is packed bf16, 0 if f32 ----
__global__ void detect_dtype(const unsigned int* __restrict__ x, int* __restrict__ flag) {
    __shared__ int s[256];
    int t = threadIdx.x;
    unsigned int u = x[t];
    unsigned int e = (u >> 7) & 0xFFu;
    s[t] = ((e >= 90u && e <= 140u) || ((u & 0xFFFFu) == 0u)) ? 1 : 0;
    __syncthreads();
    for (int off = 128; off > 0; off >>= 1) { if (t < off) s[t] += s[t + off]; __syncthreads(); }
    if (t == 0) *flag = (s[0] >= 128) ? 1 : 0;
}

// ---- fused weight conversion: all 20 tensors in one launch ----
struct CvtTable {
    const void* src[20];
    int off[20];     // dst offset into wsf
    int n[20];
    int total;
};
__global__ __launch_bounds__(256) void cvt_all(CvtTable tab, float* __restrict__ wsf,
                                               const int* __restrict__ flagp) {
    int i = blockIdx.x * 256 + threadIdx.x;
    if (i >= tab.total) return;
    int k = 0;
    while (i >= tab.n[k]) { i -= tab.n[k]; ++k; }
    float v;
    if (*flagp) v = b2f(((const unsigned short*)tab.src[k])[i]);
    else        v = ((const float*)tab.src[k])[i];
    wsf[tab.off[k] + i] = v;
}

// ---- per-layer in-degree histogram ----
__global__ __launch_bounds__(256) void deg_count(const int* __restrict__ dst, int nE,
                                                 float* __restrict__ deg) {
    int e = blockIdx.x * 256 + threadIdx.x;
    if (e < nE) atomicAdd(&deg[dst[e]], 1.0f);
}

// ---- edge scatter (segment sum) into dst window [lo,hi); flagp!=null => h may be bf16 ----
__global__ __launch_bounds__(256) void scatter_one(
    const void* __restrict__ hv, const int* __restrict__ flagp,
    const int* __restrict__ src, const int* __restrict__ dst,
    const int* __restrict__ gather, int nE, int lo, int hi,
    float* __restrict__ agg)
{
    int e = blockIdx.x * 2 + (threadIdx.x >> 7);
    int f = threadIdx.x & 127;
    if (e >= nE) return;
    int d = dst[e];
    if (d < lo || d >= hi) return;              // uniform across the 128-thread half-block
    int s = src[e];
    if (gather) s = gather[s];
    size_t idx = (size_t)s * DD + f;
    int abf = flagp ? *flagp : 0;
    float v = abf ? b2f(((const unsigned short*)hv)[idx]) : ((const float*)hv)[idx];
    atomicAdd(&agg[(size_t)(d - lo) * DD + f], v);
}

// ---- [M x 128] @ [128 x 128] GEMM, all f32; W staged in LDS in two K=64 halves ----
__global__ __launch_bounds__(256) void gemm128(
    const void* __restrict__ Av, const int* __restrict__ flagp,
    const int* __restrict__ gather, const float* __restrict__ degl,
    const float* __restrict__ W, const float* __restrict__ bias,
    float* __restrict__ out, int M, int accum, int relu)
{
    __shared__ float As[32][129];
    __shared__ float Wsm[64 * DD];
    const int tid = threadIdx.x;
    const int rb = blockIdx.x * 32;
    const int abf = flagp ? *flagp : 0;

    { // stage A tile: 32 rows x 128
        int r = tid >> 3, c0 = (tid & 7) * 16;
        int gr = rb + r;
        if (gr < M) {
            int ar = gather ? gather[gr] : gr;
            float sc = degl ? 1.0f / fmaxf(degl[gr], 1.0f) : 1.0f;
            size_t base = (size_t)ar * DD + c0;
            if (abf) {
                const unsigned short* Ab = (const unsigned short*)Av;
#pragma unroll
                for (int j = 0; j < 16; ++j) As[r][c0 + j] = sc * b2f(Ab[base + j]);
            } else {
                const float* Af = (const float*)Av;
#pragma unroll
                for (int j = 0; j < 16; ++j) As[r][c0 + j] = sc * Af[base + j];
            }
        } else {
#pragma unroll
            for (int j = 0; j < 16; ++j) As[r][c0 + j] = 0.0f;
        }
    }

    const int tx = tid & 31, ty = tid >> 5;
    const int c = tx * 4;
    float acc[4][4] = {};

#pragma unroll
    for (int half = 0; half < 2; ++half) {
        __syncthreads();
        {
            const float4* wsrc = (const float4*)(W + half * 64 * DD);
            float4* wdst = (float4*)Wsm;
#pragma unroll
            for (int i = 0; i < 8; ++i) wdst[i * 256 + tid] = wsrc[i * 256 + tid];
        }
        __syncthreads();
#pragma unroll 2
        for (int k2 = 0; k2 < 64; ++k2) {
            float4 wv = *(const float4*)&Wsm[k2 * DD + c];
            int k = half * 64 + k2;
            float a[4] = { As[ty][k], As[ty + 8][k], As[ty + 16][k], As[ty + 24][k] };
            float w[4] = { wv.x, wv.y, wv.z, wv.w };
#pragma unroll
            for (int i = 0; i < 4; ++i)
#pragma unroll
                for (int j = 0; j < 4; ++j) acc[i][j] = fmaf(a[i], w[j], acc[i][j]);
        }
    }

#pragma unroll
    for (int i = 0; i < 4; ++i) {
        int r = rb + ty + 8 * i;
        if (r >= M) continue;
        float* orow = out + (size_t)r * DD + c;
#pragma unroll
        for (int j = 0; j < 4; ++j) {
            float v = acc[i][j];
            if (bias) v += bias[c + j];
            if (accum) v += orow[j];
            if (relu) v = fmaxf(v, 0.0f);
            orow[j] = v;
        }
    }
}

// ---- column stats stage 1: per-block partial sum/sumsq (no atomics) ----
__global__ __launch_bounds__(256) void colstats_p1(
    const float* __restrict__ t, int M,
    float* __restrict__ PS, float* __restrict__ PQ)  // [NBLK][128] each
{
    __shared__ float sm[256], sq2[256];
    int tid = threadIdx.x;
    int c = tid & 127, h = tid >> 7;
    int rpb = (M + NBLK - 1) / NBLK;
    int r0 = blockIdx.x * rpb;
    int r1 = min(r0 + rpb, M);
    float s = 0.0f, ss = 0.0f;
    for (int r = r0 + h; r < r1; r += 2) {
        float v = t[(size_t)r * DD + c];
        s += v; ss += v * v;
    }
    sm[tid] = s; sq2[tid] = ss;
    __syncthreads();
    if (tid < 128) {
        PS[blockIdx.x * 128 + tid] = sm[tid] + sm[tid + 128];
        PQ[blockIdx.x * 128 + tid] = sq2[tid] + sq2[tid + 128];
    }
}

// ---- column stats stage 2: reduce partials, write final sum/sumsq (no memset needed) ----
__global__ void colstats_p2(const float* __restrict__ PS, const float* __restrict__ PQ,
                            float* __restrict__ sum, float* __restrict__ sumsq) {
    int t = threadIdx.x;  // 256
    float a = 0.0f;
    if (t < 128) {
        for (int b = 0; b < NBLK; ++b) a += PS[b * 128 + t];
        sum[t] = a;
    } else {
        int c = t - 128;
        for (int b = 0; b < NBLK; ++b) a += PQ[b * 128 + c];
        sumsq[c] = a;
    }
}

// ---- BN (population stats) + ReLU, in place, float4 ----
__global__ __launch_bounds__(256) void bn_relu(
    float* __restrict__ h, int M, const float* __restrict__ sum, const float* __restrict__ sumsq,
    const float* __restrict__ gamma, const float* __restrict__ beta) {
    size_t i4 = (size_t)blockIdx.x * blockDim.x + threadIdx.x;
    size_t n4 = (size_t)M * 32;
    if (i4 >= n4) return;
    int c = (i4 & 31) * 4;
    float4 v = ((float4*)h)[i4];
    float inv[4], m[4], g[4], be[4];
#pragma unroll
    for (int j = 0; j < 4; ++j) {
        m[j] = sum[c + j] / (float)M;
        float var = fmaxf(sumsq[c + j] / (float)M - m[j] * m[j], 0.0f);
        inv[j] = rsqrtf(var + BN_EPS);
        g[j] = gamma[c + j]; be[j] = beta[c + j];
    }
    v.x = fmaxf(g[0] * (v.x - m[0]) * inv[0] + be[0], 0.0f);
    v.y = fmaxf(g[1] * (v.y - m[1]) * inv[1] + be[1], 0.0f);
    v.z = fmaxf(g[2] * (v.z - m[2]) * inv[2] + be[2], 0.0f);
    v.w = fmaxf(g[3] * (v.w - m[3]) * inv[3] + be[3], 0.0f);
    ((float4*)h)[i4] = v;
}

// ---- summary = sigmoid(colmean(P)); ws = disc_W @ summary ----
__global__ void make_ws(const float* __restrict__ colsum, const float* __restrict__ discW,
                        float* __restrict__ wsv, int M) {
    __shared__ float s[128];
    int t = threadIdx.x;  // 128
    s[t] = 1.0f / (1.0f + expf(-(colsum[t] / (float)M)));
    __syncthreads();
    float acc = 0.0f;
    for (int j = 0; j < 128; ++j) acc += discW[t * 128 + j] * s[j];
    wsv[t] = acc;
}

// ---- loss stage 1: per-block partial softplus sums (register acc, no atomics) ----
__global__ __launch_bounds__(256) void loss_partial(
    const float* __restrict__ P, const float* __restrict__ Ng,
    const float* __restrict__ wsv, float* __restrict__ lossP, float* __restrict__ lossN, int M)
{
    __shared__ float sP[4], sN[4];
    int lane = threadIdx.x & 63;
    int wave = threadIdx.x >> 6;
    int gw = blockIdx.x * 4 + wave;
    int nw = gridDim.x * 4;
    float w0 = wsv[lane], w1 = wsv[lane + 64];
    float accP = 0.0f, accN = 0.0f;
    for (int row = gw; row < 2 * M; row += nw) {
        const float* base = (row < M) ? &P[(size_t)row * DD] : &Ng[(size_t)(row - M) * DD];
        float a = base[lane] * w0 + base[lane + 64] * w1;
#pragma unroll
        for (int off = 32; off > 0; off >>= 1) a += __shfl_down(a, off, 64);
        if (lane == 0) {
            float x = (row < M) ? -a : a;
            float sp = fmaxf(x, 0.0f) + log1pf(expf(-fabsf(x)));
            if (row < M) accP += sp; else accN += sp;
        }
    }
    if (lane == 0) { sP[wave] = accP; sN[wave] = accN; }
    __syncthreads();
    if (threadIdx.x == 0) {
        lossP[blockIdx.x] = sP[0] + sP[1] + sP[2] + sP[3];
        lossN[blockIdx.x] = sN[0] + sN[1] + sN[2] + sN[3];
    }
}

// ---- loss stage 2: reduce NBLK partials, write scalar ----
__global__ void write_loss(const float* __restrict__ lossP, const float* __restrict__ lossN,
                           void* __restrict__ outv, int M, const int* __restrict__ flagp) {
    __shared__ float s[256];
    int t = threadIdx.x;  // 256
    s[t] = (t < NBLK) ? (lossP[t] + lossN[t]) : 0.0f;
    __syncthreads();
    for (int off = 128; off > 0; off >>= 1) { if (t < off) s[t] += s[t + off]; __syncthreads(); }
    if (t == 0) {
        float v = s[0] / (float)M;
        if (*flagp) ((bf16*)outv)[20000] = __float2bfloat16(v);
        else        ((float*)outv)[20000] = v;
    }
}

// ---- predictor input: Z[i] = P[a]*P[b] ----
__global__ __launch_bounds__(256) void pair_mult(
    const float* __restrict__ P, const int* __restrict__ s_idx, const int* __restrict__ d_idx,
    float* __restrict__ Z, int nPair) {
    int i = blockIdx.x * 2 + (threadIdx.x >> 7);
    int f = threadIdx.x & 127;
    if (i >= nPair) return;
    Z[(size_t)i * DD + f] = P[(size_t)s_idx[i] * DD + f] * P[(size_t)d_idx[i] * DD + f];
}

// ---- final 128 -> 1 matvec ----
__global__ __launch_bounds__(256) void final_mv(
    const float* __restrict__ ZB, const float* __restrict__ pW3, const float* __restrict__ pb3,
    void* __restrict__ outv, int nRows, int outOff, const int* __restrict__ flagp) {
    int row = blockIdx.x * 4 + (threadIdx.x >> 6);
    int lane = threadIdx.x & 63;
    if (row >= nRows) return;
    float a = ZB[(size_t)row * DD + lane] * pW3[lane]
            + ZB[(size_t)row * DD + lane + 64] * pW3[lane + 64];
#pragma unroll
    for (int off = 32; off > 0; off >>= 1) a += __shfl_down(a, off, 64);
    if (lane == 0) {
        float v = a + pb3[0];
        if (*flagp) ((bf16*)outv)[outOff + row] = __float2bfloat16(v);
        else        ((float*)outv)[outOff + row] = v;
    }
}

extern "C" void kernel_launch(void* const* d_in, const int* in_sizes, int n_in,
                              void* d_out, int out_size, void* d_ws, size_t ws_size,
                              hipStream_t stream)
{
    const void* x      = d_in[0];
    const int* srcA[3] = {(const int*)d_in[1], (const int*)d_in[3], (const int*)d_in[5]};
    const int* dstA[3] = {(const int*)d_in[2], (const int*)d_in[4], (const int*)d_in[6]};
    const int* perm    = (const int*)d_in[7];
    const int* pos_src = (const int*)d_in[8];
    const int* pos_dst = (const int*)d_in[9];
    const int* neg_src = (const int*)d_in[10];
    const int* neg_dst = (const int*)d_in[11];

    const int N1 = 50000, N2 = 25000, N3 = 12500;
    const int E[3] = {750000, 250000, 125000};
    const int EP = 10000;

    // ---- ws layout (float offsets) ----
    float* wsf = (float*)d_ws;
    int*   flagp = (int*)d_ws;                    // [0]
    float* PS    = wsf + 256;                     // NBLK*128 = 20480
    float* PQ    = wsf + 20736;                   // 20480
    float* lossP = wsf + 41216;                   // NBLK
    float* lossN = wsf + 41376;                   // NBLK
    float* sumS  = wsf + 41600;                   // 128
    float* sqS   = wsf + 41728;                   // 128
    float* wsvec = wsf + 41856;                   // 128
    float* deg0  = wsf + 43008;                   // 50048
    float* deg1  = wsf + 93056;                   // 25024
    float* deg2  = wsf + 118080;                  // 12544 (ends 130624)
    const size_t WfB = 131072;
    float* WS[3] = {wsf + WfB +      0, wsf + WfB +  32896, wsf + WfB +  65792};
    float* WN[3] = {wsf + WfB +  16384, wsf + WfB +  49280, wsf + WfB +  82176};
    float* BV[3] = {wsf + WfB +  32768, wsf + WfB +  65664, wsf + WfB +  98560};
    float* G0  = wsf + WfB +  98688; float* BE0 = wsf + WfB +  98816;
    float* G1  = wsf + WfB +  98944; float* BE1 = wsf + WfB +  99072;
    float* DW  = wsf + WfB +  99200;
    float* PW1 = wsf + WfB + 115584; float* PB1 = wsf + WfB + 131968;
    float* PW2 = wsf + WfB + 132096; float* PB2 = wsf + WfB + 148480;
    float* PW3 = wsf + WfB + 148608; float* PB3 = wsf + WfB + 148736;
    float* PF  = wsf + 280576;                    // 1,600,000
    float* NF  = wsf + 1880576;                   // 1,600,000
    float* H2  = wsf + 3480576;                   // 3,200,000
    float* H1  = wsf + 6680576;                   // 6,400,000
    float* AGG = wsf + 13080576;                  // aggRows*128
    // predictor overlays in dead H1:
    float* Z  = H1;
    float* ZA = H1 + 1280000;
    float* ZB = H1 + 2560000;

    // choose AGG rows from ws_size (constant per process -> graph-safe)
    int aggRows = 12500;
    if (ws_size >= (size_t)(13080576 + 50000 * 128) * 4) aggRows = 50000;
    else if (ws_size >= (size_t)(13080576 + 25000 * 128) * 4) aggRows = 25000;

    // ---- dtype detect + fused weight conversion ----
    detect_dtype<<<1, 256, 0, stream>>>((const unsigned int*)x, flagp);
    CvtTable tab;
    const int widx[20] = {12,13,14, 15,16,17, 18,19,20, 21,22,23,24, 25, 26,27, 28,29, 30,31};
    float* wdst[20] = {WS[0],WN[0],BV[0], WS[1],WN[1],BV[1], WS[2],WN[2],BV[2],
                       G0,BE0,G1,BE1, DW, PW1,PB1, PW2,PB2, PW3,PB3};
    const int wn[20] = {16384,16384,128, 16384,16384,128, 16384,16384,128,
                        128,128,128,128, 16384, 16384,128, 16384,128, 128,1};
    int tot = 0;
    for (int k = 0; k < 20; ++k) {
        tab.src[k] = d_in[widx[k]];
        tab.off[k] = (int)(wdst[k] - wsf);
        tab.n[k] = wn[k];
        tot += wn[k];
    }
    tab.total = tot;
    cvt_all<<<(tot + 255) / 256, 256, 0, stream>>>(tab, wsf, flagp);

    // ---- degrees (dst-only; shared by both passes) ----
    hipMemsetAsync(deg0, 0, (size_t)(50048 + 25024 + 12544) * 4, stream);
    deg_count<<<(E[0] + 255) / 256, 256, 0, stream>>>(dstA[0], E[0], deg0);
    deg_count<<<(E[1] + 255) / 256, 256, 0, stream>>>(dstA[1], E[1], deg1);
    deg_count<<<(E[2] + 255) / 256, 256, 0, stream>>>(dstA[2], E[2], deg2);

    for (int pass = 0; pass < 2; ++pass) {
        const int* g = (pass == 0) ? nullptr : perm;
        float* OUT = (pass == 0) ? PF : NF;

        // ===== layer 0 (M=50000) =====
        gemm128<<<(N1 + 31) / 32, 256, 0, stream>>>(
            x, flagp, g, nullptr, WS[0], BV[0], H1, N1, 0, 0);
        for (int lo = 0; lo < N1; lo += aggRows) {
            int ch = min(aggRows, N1 - lo);
            hipMemsetAsync(AGG, 0, (size_t)ch * DD * 4, stream);
            scatter_one<<<(E[0] + 1) / 2, 256, 0, stream>>>(
                x, flagp, srcA[0], dstA[0], g, E[0], lo, lo + ch, AGG);
            gemm128<<<(ch + 31) / 32, 256, 0, stream>>>(
                AGG, nullptr, nullptr, deg0 + lo, WN[0], nullptr, H1 + (size_t)lo * DD, ch, 1, 0);
        }
        colstats_p1<<<NBLK, 256, 0, stream>>>(H1, N1, PS, PQ);
        colstats_p2<<<1, 256, 0, stream>>>(PS, PQ, sumS, sqS);
        bn_relu<<<((size_t)N1 * 32 + 255) / 256, 256, 0, stream>>>(H1, N1, sumS, sqS, G0, BE0);

        // ===== layer 1 (M=25000) =====
        gemm128<<<(N2 + 31) / 32, 256, 0, stream>>>(
            H1, nullptr, nullptr, nullptr, WS[1], BV[1], H2, N2, 0, 0);
        for (int lo = 0; lo < N2; lo += aggRows) {
            int ch = min(aggRows, N2 - lo);
            hipMemsetAsync(AGG, 0, (size_t)ch * DD * 4, stream);
            scatter_one<<<(E[1] + 1) / 2, 256, 0, stream>>>(
                H1, nullptr, srcA[1], dstA[1], nullptr, E[1], lo, lo + ch, AGG);
            gemm128<<<(ch + 31) / 32, 256, 0, stream>>>(
                AGG, nullptr, nullptr, deg1 + lo, WN[1], nullptr, H2 + (size_t)lo * DD, ch, 1, 0);
        }
        colstats_p1<<<NBLK, 256, 0, stream>>>(H2, N2, PS, PQ);
        colstats_p2<<<1, 256, 0, stream>>>(PS, PQ, sumS, sqS);
        bn_relu<<<((size_t)N2 * 32 + 255) / 256, 256, 0, stream>>>(H2, N2, sumS, sqS, G1, BE1);

        // ===== layer 2 (M=12500), no BN =====
        gemm128<<<(N3 + 31) / 32, 256, 0, stream>>>(
            H2, nullptr, nullptr, nullptr, WS[2], BV[2], OUT, N3, 0, 0);
        hipMemsetAsync(AGG, 0, (size_t)N3 * DD * 4, stream);
        scatter_one<<<(E[2] + 1) / 2, 256, 0, stream>>>(
            H2, nullptr, srcA[2], dstA[2], nullptr, E[2], 0, N3, AGG);
        gemm128<<<(N3 + 31) / 32, 256, 0, stream>>>(
            AGG, nullptr, nullptr, deg2, WN[2], nullptr, OUT, N3, 1, 0);
    }

    // ---- summary / discriminator loss ----
    colstats_p1<<<NBLK, 256, 0, stream>>>(PF, N3, PS, PQ);
    colstats_p2<<<1, 256, 0, stream>>>(PS, PQ, sumS, sqS);
    make_ws<<<1, 128, 0, stream>>>(sumS, DW, wsvec, N3);
    loss_partial<<<NBLK, 256, 0, stream>>>(PF, NF, wsvec, lossP, lossN, N3);
    write_loss<<<1, 256, 0, stream>>>(lossP, lossN, d_out, N3, flagp);

    // ---- predictor MLP: pos pairs then neg pairs ----
    for (int c = 0; c < 2; ++c) {
        const int* si = (c == 0) ? pos_src : neg_src;
        const int* di = (c == 0) ? pos_dst : neg_dst;
        pair_mult<<<(EP + 1) / 2, 256, 0, stream>>>(PF, si, di, Z, EP);
        gemm128<<<(EP + 31) / 32, 256, 0, stream>>>(Z,  nullptr, nullptr, nullptr, PW1, PB1, ZA, EP, 0, 1);
        gemm128<<<(EP + 31) / 32, 256, 0, stream>>>(ZA, nullptr, nullptr, nullptr, PW2, PB2, ZB, EP, 0, 1);
        final_mv<<<(EP + 3) / 4, 256, 0, stream>>>(ZB, PW3, PB3, d_out, EP, c * EP, flagp);
    }
}

// Round 7
// 1572.298 us; speedup vs baseline: 1.9655x; 1.2598x over previous
//
#include <hip/hip_runtime.h>
#include <hip/hip_bf16.h>

#define DD 128
#define BN_EPS 1e-5f
#define NBLK 160   // blocks for stats/loss partial kernels

typedef __hip_bfloat16 bf16;

__device__ __forceinline__ float b2f(unsigned short u) {
    union { float f; unsigned int i; } x; x.i = ((unsigned int)u) << 16; return x.f;
}

// ---- dtype detect: flag=1 if d_in[0] is packed bf16, 0 if f32 ----
__global__ void detect_dtype(const unsigned int* __restrict__ x, int* __restrict__ flag) {
    __shared__ int s[256];
    int t = threadIdx.x;
    unsigned int u = x[t];
    unsigned int e = (u >> 7) & 0xFFu;
    s[t] = ((e >= 90u && e <= 140u) || ((u & 0xFFFFu) == 0u)) ? 1 : 0;
    __syncthreads();
    for (int off = 128; off > 0; off >>= 1) { if (t < off) s[t] += s[t + off]; __syncthreads(); }
    if (t == 0) *flag = (s[0] >= 128) ? 1 : 0;
}

// ---- fused weight conversion: all 20 tensors in one launch ----
struct CvtTable {
    const void* src[20];
    int off[20];
    int n[20];
    int total;
};
__global__ __launch_bounds__(256) void cvt_all(CvtTable tab, float* __restrict__ wsf,
                                               const int* __restrict__ flagp) {
    int i = blockIdx.x * 256 + threadIdx.x;
    if (i >= tab.total) return;
    int k = 0;
    while (i >= tab.n[k]) { i -= tab.n[k]; ++k; }
    float v;
    if (*flagp) v = b2f(((const unsigned short*)tab.src[k])[i]);
    else        v = ((const float*)tab.src[k])[i];
    wsf[tab.off[k] + i] = v;
}

// ---- CSR build: int in-degree histogram ----
__global__ __launch_bounds__(256) void hist_count(const int* __restrict__ dst, int nE,
                                                  int* __restrict__ cnt) {
    int e = blockIdx.x * 256 + threadIdx.x;
    if (e < nE) atomicAdd(&cnt[dst[e]], 1);
}

// ---- CSR build: exclusive scan (single block, 256 threads, chunked) ----
__global__ __launch_bounds__(256) void exscan(const int* __restrict__ cnt, int n,
                                              int* __restrict__ rowptr) {
    __shared__ int wsum[4];
    __shared__ int totS;
    int t = threadIdx.x, lane = t & 63, w = t >> 6;
    int chunk = (n + 255) / 256;
    int lo = t * chunk, hi = min(lo + chunk, n);
    if (lo > n) lo = n;
    if (hi < lo) hi = lo;
    int s = 0;
    for (int i = lo; i < hi; ++i) s += cnt[i];
    int inc = s;
    for (int off = 1; off < 64; off <<= 1) {
        int u = __shfl_up(inc, off, 64);
        if (lane >= off) inc += u;
    }
    if (lane == 63) wsum[w] = inc;
    __syncthreads();
    int wo = 0;
    for (int i = 0; i < w; ++i) wo += wsum[i];
    int excl = wo + inc - s;
    if (t == 255) totS = wo + inc;
    __syncthreads();
    int acc = excl;
    for (int i = lo; i < hi; ++i) { rowptr[i] = acc; acc += cnt[i]; }
    if (t == 255) rowptr[n] = totS;
}

// ---- CSR build: fill edge ids sorted by dst ----
__global__ __launch_bounds__(256) void csr_fill(
    const int* __restrict__ src, const int* __restrict__ dst, int nE,
    const int* __restrict__ rowptr, int* __restrict__ cursor, int* __restrict__ eid) {
    int e = blockIdx.x * 256 + threadIdx.x;
    if (e >= nE) return;
    int d = dst[e];
    int pos = rowptr[d] + atomicAdd(&cursor[d], 1);
    eid[pos] = src[e];
}

// ---- CSR gather: mean over in-neighbors for dst rows [lo,hi), local out rows ----
__global__ __launch_bounds__(256) void gather_mean(
    const void* __restrict__ hv, const int* __restrict__ flagp, const int* __restrict__ perm,
    const int* __restrict__ rowptr, const int* __restrict__ eid,
    int lo, int hi, float* __restrict__ out)
{
    int d = lo + blockIdx.x * 2 + (threadIdx.x >> 7);
    int f = threadIdx.x & 127;
    if (d >= hi) return;
    int i0 = rowptr[d], i1 = rowptr[d + 1];
    float s = 0.0f;
    int abf = flagp ? *flagp : 0;
    if (abf) {
        const unsigned short* h = (const unsigned short*)hv;
        for (int i = i0; i < i1; ++i) {
            int sid = eid[i];
            if (perm) sid = perm[sid];
            s += b2f(h[(size_t)sid * DD + f]);
        }
    } else {
        const float* h = (const float*)hv;
        for (int i = i0; i < i1; ++i) {
            int sid = eid[i];
            if (perm) sid = perm[sid];
            s += h[(size_t)sid * DD + f];
        }
    }
    out[(size_t)(d - lo) * DD + f] = s / fmaxf((float)(i1 - i0), 1.0f);
}

// ---- [M x 128] @ [128 x 128] GEMM, all f32; W staged in LDS in two K=64 halves ----
__global__ __launch_bounds__(256) void gemm128(
    const void* __restrict__ Av, const int* __restrict__ flagp,
    const int* __restrict__ gather,
    const float* __restrict__ W, const float* __restrict__ bias,
    float* __restrict__ out, int M, int accum, int relu)
{
    __shared__ float As[32][129];
    __shared__ float Wsm[64 * DD];
    const int tid = threadIdx.x;
    const int rb = blockIdx.x * 32;
    const int abf = flagp ? *flagp : 0;

    { // stage A tile: 32 rows x 128
        int r = tid >> 3, c0 = (tid & 7) * 16;
        int gr = rb + r;
        if (gr < M) {
            int ar = gather ? gather[gr] : gr;
            size_t base = (size_t)ar * DD + c0;
            if (abf) {
                const unsigned short* Ab = (const unsigned short*)Av;
#pragma unroll
                for (int j = 0; j < 16; ++j) As[r][c0 + j] = b2f(Ab[base + j]);
            } else {
                const float* Af = (const float*)Av;
#pragma unroll
                for (int j = 0; j < 16; ++j) As[r][c0 + j] = Af[base + j];
            }
        } else {
#pragma unroll
            for (int j = 0; j < 16; ++j) As[r][c0 + j] = 0.0f;
        }
    }

    const int tx = tid & 31, ty = tid >> 5;
    const int c = tx * 4;
    float acc[4][4] = {};

#pragma unroll
    for (int half = 0; half < 2; ++half) {
        __syncthreads();
        {
            const float4* wsrc = (const float4*)(W + half * 64 * DD);
            float4* wdst = (float4*)Wsm;
#pragma unroll
            for (int i = 0; i < 8; ++i) wdst[i * 256 + tid] = wsrc[i * 256 + tid];
        }
        __syncthreads();
#pragma unroll 2
        for (int k2 = 0; k2 < 64; ++k2) {
            float4 wv = *(const float4*)&Wsm[k2 * DD + c];
            int k = half * 64 + k2;
            float a[4] = { As[ty][k], As[ty + 8][k], As[ty + 16][k], As[ty + 24][k] };
            float w[4] = { wv.x, wv.y, wv.z, wv.w };
#pragma unroll
            for (int i = 0; i < 4; ++i)
#pragma unroll
                for (int j = 0; j < 4; ++j) acc[i][j] = fmaf(a[i], w[j], acc[i][j]);
        }
    }

#pragma unroll
    for (int i = 0; i < 4; ++i) {
        int r = rb + ty + 8 * i;
        if (r >= M) continue;
        float* orow = out + (size_t)r * DD + c;
#pragma unroll
        for (int j = 0; j < 4; ++j) {
            float v = acc[i][j];
            if (bias) v += bias[c + j];
            if (accum) v += orow[j];
            if (relu) v = fmaxf(v, 0.0f);
            orow[j] = v;
        }
    }
}

// ---- column stats stage 1: per-block partials (no atomics) ----
__global__ __launch_bounds__(256) void colstats_p1(
    const float* __restrict__ t, int M,
    float* __restrict__ PS, float* __restrict__ PQ)
{
    __shared__ float sm[256], sq2[256];
    int tid = threadIdx.x;
    int c = tid & 127, h = tid >> 7;
    int rpb = (M + NBLK - 1) / NBLK;
    int r0 = blockIdx.x * rpb;
    int r1 = min(r0 + rpb, M);
    float s = 0.0f, ss = 0.0f;
    for (int r = r0 + h; r < r1; r += 2) {
        float v = t[(size_t)r * DD + c];
        s += v; ss += v * v;
    }
    sm[tid] = s; sq2[tid] = ss;
    __syncthreads();
    if (tid < 128) {
        PS[blockIdx.x * 128 + tid] = sm[tid] + sm[tid + 128];
        PQ[blockIdx.x * 128 + tid] = sq2[tid] + sq2[tid + 128];
    }
}

// ---- column stats stage 2 ----
__global__ void colstats_p2(const float* __restrict__ PS, const float* __restrict__ PQ,
                            float* __restrict__ sum, float* __restrict__ sumsq) {
    int t = threadIdx.x;  // 256
    float a = 0.0f;
    if (t < 128) {
        for (int b = 0; b < NBLK; ++b) a += PS[b * 128 + t];
        sum[t] = a;
    } else {
        int c = t - 128;
        for (int b = 0; b < NBLK; ++b) a += PQ[b * 128 + c];
        sumsq[c] = a;
    }
}

// ---- BN + ReLU, in place, float4 ----
__global__ __launch_bounds__(256) void bn_relu(
    float* __restrict__ h, int M, const float* __restrict__ sum, const float* __restrict__ sumsq,
    const float* __restrict__ gamma, const float* __restrict__ beta) {
    size_t i4 = (size_t)blockIdx.x * blockDim.x + threadIdx.x;
    size_t n4 = (size_t)M * 32;
    if (i4 >= n4) return;
    int c = (i4 & 31) * 4;
    float4 v = ((float4*)h)[i4];
    float inv[4], m[4], g[4], be[4];
#pragma unroll
    for (int j = 0; j < 4; ++j) {
        m[j] = sum[c + j] / (float)M;
        float var = fmaxf(sumsq[c + j] / (float)M - m[j] * m[j], 0.0f);
        inv[j] = rsqrtf(var + BN_EPS);
        g[j] = gamma[c + j]; be[j] = beta[c + j];
    }
    v.x = fmaxf(g[0] * (v.x - m[0]) * inv[0] + be[0], 0.0f);
    v.y = fmaxf(g[1] * (v.y - m[1]) * inv[1] + be[1], 0.0f);
    v.z = fmaxf(g[2] * (v.z - m[2]) * inv[2] + be[2], 0.0f);
    v.w = fmaxf(g[3] * (v.w - m[3]) * inv[3] + be[3], 0.0f);
    ((float4*)h)[i4] = v;
}

// ---- summary = sigmoid(colmean(P)); ws = disc_W @ summary ----
__global__ void make_ws(const float* __restrict__ colsum, const float* __restrict__ discW,
                        float* __restrict__ wsv, int M) {
    __shared__ float s[128];
    int t = threadIdx.x;  // 128
    s[t] = 1.0f / (1.0f + expf(-(colsum[t] / (float)M)));
    __syncthreads();
    float acc = 0.0f;
    for (int j = 0; j < 128; ++j) acc += discW[t * 128 + j] * s[j];
    wsv[t] = acc;
}

// ---- loss stage 1: per-block partial softplus sums ----
__global__ __launch_bounds__(256) void loss_partial(
    const float* __restrict__ P, const float* __restrict__ Ng,
    const float* __restrict__ wsv, float* __restrict__ lossP, float* __restrict__ lossN, int M)
{
    __shared__ float sP[4], sN[4];
    int lane = threadIdx.x & 63;
    int wave = threadIdx.x >> 6;
    int gw = blockIdx.x * 4 + wave;
    int nw = gridDim.x * 4;
    float w0 = wsv[lane], w1 = wsv[lane + 64];
    float accP = 0.0f, accN = 0.0f;
    for (int row = gw; row < 2 * M; row += nw) {
        const float* base = (row < M) ? &P[(size_t)row * DD] : &Ng[(size_t)(row - M) * DD];
        float a = base[lane] * w0 + base[lane + 64] * w1;
#pragma unroll
        for (int off = 32; off > 0; off >>= 1) a += __shfl_down(a, off, 64);
        if (lane == 0) {
            float x = (row < M) ? -a : a;
            float sp = fmaxf(x, 0.0f) + log1pf(expf(-fabsf(x)));
            if (row < M) accP += sp; else accN += sp;
        }
    }
    if (lane == 0) { sP[wave] = accP; sN[wave] = accN; }
    __syncthreads();
    if (threadIdx.x == 0) {
        lossP[blockIdx.x] = sP[0] + sP[1] + sP[2] + sP[3];
        lossN[blockIdx.x] = sN[0] + sN[1] + sN[2] + sN[3];
    }
}

// ---- loss stage 2 ----
__global__ void write_loss(const float* __restrict__ lossP, const float* __restrict__ lossN,
                           void* __restrict__ outv, int M, const int* __restrict__ flagp) {
    __shared__ float s[256];
    int t = threadIdx.x;  // 256
    s[t] = (t < NBLK) ? (lossP[t] + lossN[t]) : 0.0f;
    __syncthreads();
    for (int off = 128; off > 0; off >>= 1) { if (t < off) s[t] += s[t + off]; __syncthreads(); }
    if (t == 0) {
        float v = s[0] / (float)M;
        if (*flagp) ((bf16*)outv)[20000] = __float2bfloat16(v);
        else        ((float*)outv)[20000] = v;
    }
}

// ---- predictor input: Z[i] = P[a]*P[b] ----
__global__ __launch_bounds__(256) void pair_mult(
    const float* __restrict__ P, const int* __restrict__ s_idx, const int* __restrict__ d_idx,
    float* __restrict__ Z, int nPair) {
    int i = blockIdx.x * 2 + (threadIdx.x >> 7);
    int f = threadIdx.x & 127;
    if (i >= nPair) return;
    Z[(size_t)i * DD + f] = P[(size_t)s_idx[i] * DD + f] * P[(size_t)d_idx[i] * DD + f];
}

// ---- final 128 -> 1 matvec ----
__global__ __launch_bounds__(256) void final_mv(
    const float* __restrict__ ZB, const float* __restrict__ pW3, const float* __restrict__ pb3,
    void* __restrict__ outv, int nRows, int outOff, const int* __restrict__ flagp) {
    int row = blockIdx.x * 4 + (threadIdx.x >> 6);
    int lane = threadIdx.x & 63;
    if (row >= nRows) return;
    float a = ZB[(size_t)row * DD + lane] * pW3[lane]
            + ZB[(size_t)row * DD + lane + 64] * pW3[lane + 64];
#pragma unroll
    for (int off = 32; off > 0; off >>= 1) a += __shfl_down(a, off, 64);
    if (lane == 0) {
        float v = a + pb3[0];
        if (*flagp) ((bf16*)outv)[outOff + row] = __float2bfloat16(v);
        else        ((float*)outv)[outOff + row] = v;
    }
}

extern "C" void kernel_launch(void* const* d_in, const int* in_sizes, int n_in,
                              void* d_out, int out_size, void* d_ws, size_t ws_size,
                              hipStream_t stream)
{
    const void* x      = d_in[0];
    const int* srcA[3] = {(const int*)d_in[1], (const int*)d_in[3], (const int*)d_in[5]};
    const int* dstA[3] = {(const int*)d_in[2], (const int*)d_in[4], (const int*)d_in[6]};
    const int* perm    = (const int*)d_in[7];
    const int* pos_src = (const int*)d_in[8];
    const int* pos_dst = (const int*)d_in[9];
    const int* neg_src = (const int*)d_in[10];
    const int* neg_dst = (const int*)d_in[11];

    const int N1 = 50000, N2 = 25000, N3 = 12500;
    const int E[3] = {750000, 250000, 125000};
    const int EP = 10000;

    // ---- ws layout (4-byte units). Peak ~17.58M = 70.3 MiB ----
    float* wsf = (float*)d_ws;
    int*   wsi = (int*)d_ws;
    int*   flagp = wsi;                           // [0]
    float* PS    = wsf + 256;                     // 20480
    float* PQ    = wsf + 20736;                   // 20480
    float* lossP = wsf + 41216;                   // 160
    float* lossN = wsf + 41376;                   // 160
    float* sumS  = wsf + 41600;                   // 128
    float* sqS   = wsf + 41728;                   // 128
    float* wsvec = wsf + 41856;                   // 128
    // CSR (ints): hist+cursor contiguous for one memset
    int* hist0 = wsi + 43008;                     // 50000
    int* hist1 = wsi + 93008;                     // 25000
    int* hist2 = wsi + 118008;                    // 12500
    int* cur0  = wsi + 130560;                    // 50000
    int* cur1  = wsi + 180560;                    // 25000
    int* cur2  = wsi + 205560;                    // 12500 (ends 218060)
    int* rp0   = wsi + 218112;                    // 50001
    int* rp1   = wsi + 268160;                    // 25001
    int* rp2   = wsi + 293248;                    // 12501
    int* eid0  = wsi + 305792;                    // 750000
    int* eid1  = wsi + 1055792;                   // 250000
    int* eid2  = wsi + 1305792;                   // 125000 (ends 1430792)
    const size_t WfB = 1431040;
    float* WS[3] = {wsf + WfB +      0, wsf + WfB +  32896, wsf + WfB +  65792};
    float* WN[3] = {wsf + WfB +  16384, wsf + WfB +  49280, wsf + WfB +  82176};
    float* BV[3] = {wsf + WfB +  32768, wsf + WfB +  65664, wsf + WfB +  98560};
    float* G0  = wsf + WfB +  98688; float* BE0 = wsf + WfB +  98816;
    float* G1  = wsf + WfB +  98944; float* BE1 = wsf + WfB +  99072;
    float* DW  = wsf + WfB +  99200;
    float* PW1 = wsf + WfB + 115584; float* PB1 = wsf + WfB + 131968;
    float* PW2 = wsf + WfB + 132096; float* PB2 = wsf + WfB + 148480;
    float* PW3 = wsf + WfB + 148608; float* PB3 = wsf + WfB + 148736;
    float* PF  = wsf + 1580032;                   // 1,600,000
    float* NF  = wsf + 3180032;                   // 1,600,000
    float* H2  = wsf + 4780032;                   // 3,200,000
    float* H1  = wsf + 7980032;                   // 6,400,000
    float* AGG = wsf + 14380032;                  // 3,200,000 (25000 rows max) -> 17,580,032
    // predictor overlays in dead H1:
    float* Z  = H1;
    float* ZA = H1 + 1280000;
    float* ZB = H1 + 2560000;

    // ---- dtype detect + fused weight conversion ----
    detect_dtype<<<1, 256, 0, stream>>>((const unsigned int*)x, flagp);
    CvtTable tab;
    const int widx[20] = {12,13,14, 15,16,17, 18,19,20, 21,22,23,24, 25, 26,27, 28,29, 30,31};
    float* wdst[20] = {WS[0],WN[0],BV[0], WS[1],WN[1],BV[1], WS[2],WN[2],BV[2],
                       G0,BE0,G1,BE1, DW, PW1,PB1, PW2,PB2, PW3,PB3};
    const int wn[20] = {16384,16384,128, 16384,16384,128, 16384,16384,128,
                        128,128,128,128, 16384, 16384,128, 16384,128, 128,1};
    int tot = 0;
    for (int k = 0; k < 20; ++k) {
        tab.src[k] = d_in[widx[k]];
        tab.off[k] = (int)(wdst[k] - wsf);
        tab.n[k] = wn[k];
        tot += wn[k];
    }
    tab.total = tot;
    cvt_all<<<(tot + 255) / 256, 256, 0, stream>>>(tab, wsf, flagp);

    // ---- CSR build (shared by both passes) ----
    hipMemsetAsync(hist0, 0, (size_t)(218060 - 43008) * 4, stream);  // hist+cursor
    int* histA[3] = {hist0, hist1, hist2};
    int* curA[3]  = {cur0, cur1, cur2};
    int* rpA[3]   = {rp0, rp1, rp2};
    int* eidA[3]  = {eid0, eid1, eid2};
    const int NdA[3] = {N1, N2, N3};
    for (int l = 0; l < 3; ++l) {
        hist_count<<<(E[l] + 255) / 256, 256, 0, stream>>>(dstA[l], E[l], histA[l]);
        exscan<<<1, 256, 0, stream>>>(histA[l], NdA[l], rpA[l]);
        csr_fill<<<(E[l] + 255) / 256, 256, 0, stream>>>(srcA[l], dstA[l], E[l],
                                                         rpA[l], curA[l], eidA[l]);
    }

    for (int pass = 0; pass < 2; ++pass) {
        const int* g = (pass == 0) ? nullptr : perm;
        float* OUT = (pass == 0) ? PF : NF;

        // ===== layer 0 (M=50000): self gemm, then 2 gather+gemm chunks =====
        gemm128<<<(N1 + 31) / 32, 256, 0, stream>>>(
            x, flagp, g, WS[0], BV[0], H1, N1, 0, 0);
        for (int lo = 0; lo < N1; lo += 25000) {
            gather_mean<<<(25000 + 1) / 2, 256, 0, stream>>>(
                x, flagp, g, rp0, eid0, lo, lo + 25000, AGG);
            gemm128<<<(25000 + 31) / 32, 256, 0, stream>>>(
                AGG, nullptr, nullptr, WN[0], nullptr, H1 + (size_t)lo * DD, 25000, 1, 0);
        }
        colstats_p1<<<NBLK, 256, 0, stream>>>(H1, N1, PS, PQ);
        colstats_p2<<<1, 256, 0, stream>>>(PS, PQ, sumS, sqS);
        bn_relu<<<((size_t)N1 * 32 + 255) / 256, 256, 0, stream>>>(H1, N1, sumS, sqS, G0, BE0);

        // ===== layer 1 (M=25000) =====
        gemm128<<<(N2 + 31) / 32, 256, 0, stream>>>(
            H1, nullptr, nullptr, WS[1], BV[1], H2, N2, 0, 0);
        gather_mean<<<(N2 + 1) / 2, 256, 0, stream>>>(
            H1, nullptr, nullptr, rp1, eid1, 0, N2, AGG);
        gemm128<<<(N2 + 31) / 32, 256, 0, stream>>>(
            AGG, nullptr, nullptr, WN[1], nullptr, H2, N2, 1, 0);
        colstats_p1<<<NBLK, 256, 0, stream>>>(H2, N2, PS, PQ);
        colstats_p2<<<1, 256, 0, stream>>>(PS, PQ, sumS, sqS);
        bn_relu<<<((size_t)N2 * 32 + 255) / 256, 256, 0, stream>>>(H2, N2, sumS, sqS, G1, BE1);

        // ===== layer 2 (M=12500), no BN =====
        gemm128<<<(N3 + 31) / 32, 256, 0, stream>>>(
            H2, nullptr, nullptr, WS[2], BV[2], OUT, N3, 0, 0);
        gather_mean<<<(N3 + 1) / 2, 256, 0, stream>>>(
            H2, nullptr, nullptr, rp2, eid2, 0, N3, AGG);
        gemm128<<<(N3 + 31) / 32, 256, 0, stream>>>(
            AGG, nullptr, nullptr, WN[2], nullptr, OUT, N3, 1, 0);
    }

    // ---- summary / discriminator loss ----
    colstats_p1<<<NBLK, 256, 0, stream>>>(PF, N3, PS, PQ);
    colstats_p2<<<1, 256, 0, stream>>>(PS, PQ, sumS, sqS);
    make_ws<<<1, 128, 0, stream>>>(sumS, DW, wsvec, N3);
    loss_partial<<<NBLK, 256, 0, stream>>>(PF, NF, wsvec, lossP, lossN, N3);
    write_loss<<<1, 256, 0, stream>>>(lossP, lossN, d_out, N3, flagp);

    // ---- predictor MLP: pos pairs then neg pairs ----
    for (int c = 0; c < 2; ++c) {
        const int* si = (c == 0) ? pos_src : neg_src;
        const int* di = (c == 0) ? pos_dst : neg_dst;
        pair_mult<<<(EP + 1) / 2, 256, 0, stream>>>(PF, si, di, Z, EP);
        gemm128<<<(EP + 31) / 32, 256, 0, stream>>>(Z,  nullptr, nullptr, PW1, PB1, ZA, EP, 0, 1);
        gemm128<<<(EP + 31) / 32, 256, 0, stream>>>(ZA, nullptr, nullptr, PW2, PB2, ZB, EP, 0, 1);
        final_mv<<<(EP + 3) / 4, 256, 0, stream>>>(ZB, PW3, PB3, d_out, EP, c * EP, flagp);
    }
}

// Round 8
// 1153.601 us; speedup vs baseline: 2.6789x; 1.3629x over previous
//
#include <hip/hip_runtime.h>
#include <hip/hip_bf16.h>

#define DD 128
#define BN_EPS 1e-5f
#define NBLK 160   // blocks for stats/loss partial kernels

typedef __hip_bfloat16 bf16;

__device__ __forceinline__ float b2f(unsigned short u) {
    union { float f; unsigned int i; } x; x.i = ((unsigned int)u) << 16; return x.f;
}

// ---- dtype detect: flag=1 if d_in[0] is packed bf16, 0 if f32 ----
__global__ void detect_dtype(const unsigned int* __restrict__ x, int* __restrict__ flag) {
    __shared__ int s[256];
    int t = threadIdx.x;
    unsigned int u = x[t];
    unsigned int e = (u >> 7) & 0xFFu;
    s[t] = ((e >= 90u && e <= 140u) || ((u & 0xFFFFu) == 0u)) ? 1 : 0;
    __syncthreads();
    for (int off = 128; off > 0; off >>= 1) { if (t < off) s[t] += s[t + off]; __syncthreads(); }
    if (t == 0) *flag = (s[0] >= 128) ? 1 : 0;
}

// ---- fused weight conversion ----
struct CvtTable {
    const void* src[20];
    int off[20];
    int n[20];
    int total;
};
__global__ __launch_bounds__(256) void cvt_all(CvtTable tab, float* __restrict__ wsf,
                                               const int* __restrict__ flagp) {
    int i = blockIdx.x * 256 + threadIdx.x;
    if (i >= tab.total) return;
    int k = 0;
    while (i >= tab.n[k]) { i -= tab.n[k]; ++k; }
    float v;
    if (*flagp) v = b2f(((const unsigned short*)tab.src[k])[i]);
    else        v = ((const float*)tab.src[k])[i];
    wsf[tab.off[k] + i] = v;
}

// ---- CSR build ----
__global__ __launch_bounds__(256) void hist_count(const int* __restrict__ dst, int nE,
                                                  int* __restrict__ cnt) {
    int e = blockIdx.x * 256 + threadIdx.x;
    if (e < nE) atomicAdd(&cnt[dst[e]], 1);
}

__global__ __launch_bounds__(256) void exscan(const int* __restrict__ cnt, int n,
                                              int* __restrict__ rowptr) {
    __shared__ int wsum[4];
    __shared__ int totS;
    int t = threadIdx.x, lane = t & 63, w = t >> 6;
    int chunk = (n + 255) / 256;
    int lo = t * chunk, hi = min(lo + chunk, n);
    if (lo > n) lo = n;
    if (hi < lo) hi = lo;
    int s = 0;
    for (int i = lo; i < hi; ++i) s += cnt[i];
    int inc = s;
    for (int off = 1; off < 64; off <<= 1) {
        int u = __shfl_up(inc, off, 64);
        if (lane >= off) inc += u;
    }
    if (lane == 63) wsum[w] = inc;
    __syncthreads();
    int wo = 0;
    for (int i = 0; i < w; ++i) wo += wsum[i];
    int excl = wo + inc - s;
    if (t == 255) totS = wo + inc;
    __syncthreads();
    int acc = excl;
    for (int i = lo; i < hi; ++i) { rowptr[i] = acc; acc += cnt[i]; }
    if (t == 255) rowptr[n] = totS;
}

__global__ __launch_bounds__(256) void csr_fill(
    const int* __restrict__ src, const int* __restrict__ dst, int nE,
    const int* __restrict__ rowptr, int* __restrict__ cursor, int* __restrict__ eid) {
    int e = blockIdx.x * 256 + threadIdx.x;
    if (e >= nE) return;
    int d = dst[e];
    int pos = rowptr[d] + atomicAdd(&cursor[d], 1);
    eid[pos] = src[e];
}

// ---- CSR gather v2: one wave per dst row, lane covers 2 features, 4-deep unroll ----
__global__ __launch_bounds__(256) void gather_mean(
    const void* __restrict__ hv, const int* __restrict__ flagp, const int* __restrict__ perm,
    const int* __restrict__ rowptr, const int* __restrict__ eid,
    int lo, int hi, float* __restrict__ out)
{
    int d = lo + blockIdx.x * 4 + (threadIdx.x >> 6);
    int lane = threadIdx.x & 63;
    if (d >= hi) return;
    int i0 = rowptr[d], i1 = rowptr[d + 1];
    int abf = flagp ? *flagp : 0;
    float a0x = 0, a0y = 0, a1x = 0, a1y = 0, a2x = 0, a2y = 0, a3x = 0, a3y = 0;
    int i = i0;
    if (abf) {
        const unsigned short* h = (const unsigned short*)hv;
        for (; i + 4 <= i1; i += 4) {
            int s0 = eid[i], s1 = eid[i + 1], s2 = eid[i + 2], s3 = eid[i + 3];
            if (perm) { s0 = perm[s0]; s1 = perm[s1]; s2 = perm[s2]; s3 = perm[s3]; }
            ushort2 v0 = *(const ushort2*)&h[(size_t)s0 * DD + lane * 2];
            ushort2 v1 = *(const ushort2*)&h[(size_t)s1 * DD + lane * 2];
            ushort2 v2 = *(const ushort2*)&h[(size_t)s2 * DD + lane * 2];
            ushort2 v3 = *(const ushort2*)&h[(size_t)s3 * DD + lane * 2];
            a0x += b2f(v0.x); a0y += b2f(v0.y);
            a1x += b2f(v1.x); a1y += b2f(v1.y);
            a2x += b2f(v2.x); a2y += b2f(v2.y);
            a3x += b2f(v3.x); a3y += b2f(v3.y);
        }
        for (; i < i1; ++i) {
            int s = eid[i];
            if (perm) s = perm[s];
            ushort2 v = *(const ushort2*)&h[(size_t)s * DD + lane * 2];
            a0x += b2f(v.x); a0y += b2f(v.y);
        }
    } else {
        const float* h = (const float*)hv;
        for (; i + 4 <= i1; i += 4) {
            int s0 = eid[i], s1 = eid[i + 1], s2 = eid[i + 2], s3 = eid[i + 3];
            if (perm) { s0 = perm[s0]; s1 = perm[s1]; s2 = perm[s2]; s3 = perm[s3]; }
            float2 v0 = *(const float2*)&h[(size_t)s0 * DD + lane * 2];
            float2 v1 = *(const float2*)&h[(size_t)s1 * DD + lane * 2];
            float2 v2 = *(const float2*)&h[(size_t)s2 * DD + lane * 2];
            float2 v3 = *(const float2*)&h[(size_t)s3 * DD + lane * 2];
            a0x += v0.x; a0y += v0.y;
            a1x += v1.x; a1y += v1.y;
            a2x += v2.x; a2y += v2.y;
            a3x += v3.x; a3y += v3.y;
        }
        for (; i < i1; ++i) {
            int s = eid[i];
            if (perm) s = perm[s];
            float2 v = *(const float2*)&h[(size_t)s * DD + lane * 2];
            a0x += v.x; a0y += v.y;
        }
    }
    float rd = 1.0f / fmaxf((float)(i1 - i0), 1.0f);
    float2 o;
    o.x = (a0x + a1x + a2x + a3x) * rd;
    o.y = (a0y + a1y + a2y + a3y) * rd;
    *(float2*)&out[(size_t)(d - lo) * DD + lane * 2] = o;
}

// ---- fused SAGE GEMM: out[lo+r] = A1[g(lo+r)] @ W1 + A2[r] @ W2 + bias, K=256 ----
__global__ __launch_bounds__(256) void gemm256(
    const void* __restrict__ A1v, const int* __restrict__ flagp,
    const int* __restrict__ gather, int lo,
    const float* __restrict__ A2,
    const float* __restrict__ W1, const float* __restrict__ W2,
    const float* __restrict__ bias,
    float* __restrict__ out, int Mc, int relu)
{
    __shared__ float As1[32][129];
    __shared__ float As2[32][129];
    __shared__ float Wsm[32 * DD];
    const int tid = threadIdx.x;
    const int rb = blockIdx.x * 32;
    const int abf = flagp ? *flagp : 0;

    { // stage both A tiles
        int r = tid >> 3, c0 = (tid & 7) * 16;
        int lr = rb + r;
        if (lr < Mc) {
            int ar = gather ? gather[lo + lr] : (lo + lr);
            size_t b1 = (size_t)ar * DD + c0;
            if (abf) {
                const unsigned short* Ab = (const unsigned short*)A1v;
#pragma unroll
                for (int j = 0; j < 16; ++j) As1[r][c0 + j] = b2f(Ab[b1 + j]);
            } else {
                const float* Af = (const float*)A1v;
#pragma unroll
                for (int j = 0; j < 16; ++j) As1[r][c0 + j] = Af[b1 + j];
            }
            const float* a2 = A2 + (size_t)lr * DD + c0;
#pragma unroll
            for (int j = 0; j < 16; ++j) As2[r][c0 + j] = a2[j];
        } else {
#pragma unroll
            for (int j = 0; j < 16; ++j) { As1[r][c0 + j] = 0.0f; As2[r][c0 + j] = 0.0f; }
        }
    }

    const int tx = tid & 31, ty = tid >> 5;
    const int c = tx * 4;
    float acc[4][4] = {};

#pragma unroll
    for (int ph = 0; ph < 8; ++ph) {
        __syncthreads();
        const float* W = (ph < 4) ? W1 : W2;
        const int q = ph & 3;
        {
            const float4* wsrc = (const float4*)(W + q * 32 * DD);
            float4* wdst = (float4*)Wsm;
#pragma unroll
            for (int i = 0; i < 4; ++i) wdst[i * 256 + tid] = wsrc[i * 256 + tid];
        }
        __syncthreads();
        float (*As)[129] = (ph < 4) ? As1 : As2;
#pragma unroll 2
        for (int k2 = 0; k2 < 32; ++k2) {
            float4 wv = *(const float4*)&Wsm[k2 * DD + c];
            int k = q * 32 + k2;
            float a[4] = { As[ty][k], As[ty + 8][k], As[ty + 16][k], As[ty + 24][k] };
            float w[4] = { wv.x, wv.y, wv.z, wv.w };
#pragma unroll
            for (int i = 0; i < 4; ++i)
#pragma unroll
                for (int j = 0; j < 4; ++j) acc[i][j] = fmaf(a[i], w[j], acc[i][j]);
        }
    }

#pragma unroll
    for (int i = 0; i < 4; ++i) {
        int r = rb + ty + 8 * i;
        if (r >= Mc) continue;
        float* orow = out + (size_t)(lo + r) * DD + c;
#pragma unroll
        for (int j = 0; j < 4; ++j) {
            float v = acc[i][j] + bias[c + j];
            if (relu) v = fmaxf(v, 0.0f);
            orow[j] = v;
        }
    }
}

// ---- plain [M x 128] @ [128 x 128] GEMM (predictor MLP) ----
__global__ __launch_bounds__(256) void gemm128(
    const float* __restrict__ A,
    const float* __restrict__ W, const float* __restrict__ bias,
    float* __restrict__ out, int M, int relu)
{
    __shared__ float As[32][129];
    __shared__ float Wsm[64 * DD];
    const int tid = threadIdx.x;
    const int rb = blockIdx.x * 32;

    {
        int r = tid >> 3, c0 = (tid & 7) * 16;
        int gr = rb + r;
        if (gr < M) {
            const float* arow = A + (size_t)gr * DD + c0;
#pragma unroll
            for (int j = 0; j < 16; ++j) As[r][c0 + j] = arow[j];
        } else {
#pragma unroll
            for (int j = 0; j < 16; ++j) As[r][c0 + j] = 0.0f;
        }
    }

    const int tx = tid & 31, ty = tid >> 5;
    const int c = tx * 4;
    float acc[4][4] = {};

#pragma unroll
    for (int half = 0; half < 2; ++half) {
        __syncthreads();
        {
            const float4* wsrc = (const float4*)(W + half * 64 * DD);
            float4* wdst = (float4*)Wsm;
#pragma unroll
            for (int i = 0; i < 8; ++i) wdst[i * 256 + tid] = wsrc[i * 256 + tid];
        }
        __syncthreads();
#pragma unroll 2
        for (int k2 = 0; k2 < 64; ++k2) {
            float4 wv = *(const float4*)&Wsm[k2 * DD + c];
            int k = half * 64 + k2;
            float a[4] = { As[ty][k], As[ty + 8][k], As[ty + 16][k], As[ty + 24][k] };
            float w[4] = { wv.x, wv.y, wv.z, wv.w };
#pragma unroll
            for (int i = 0; i < 4; ++i)
#pragma unroll
                for (int j = 0; j < 4; ++j) acc[i][j] = fmaf(a[i], w[j], acc[i][j]);
        }
    }

#pragma unroll
    for (int i = 0; i < 4; ++i) {
        int r = rb + ty + 8 * i;
        if (r >= M) continue;
        float* orow = out + (size_t)r * DD + c;
#pragma unroll
        for (int j = 0; j < 4; ++j) {
            float v = acc[i][j] + bias[c + j];
            if (relu) v = fmaxf(v, 0.0f);
            orow[j] = v;
        }
    }
}

// ---- column stats stage 1 ----
__global__ __launch_bounds__(256) void colstats_p1(
    const float* __restrict__ t, int M,
    float* __restrict__ PS, float* __restrict__ PQ)
{
    __shared__ float sm[256], sq2[256];
    int tid = threadIdx.x;
    int c = tid & 127, h = tid >> 7;
    int rpb = (M + NBLK - 1) / NBLK;
    int r0 = blockIdx.x * rpb;
    int r1 = min(r0 + rpb, M);
    float s = 0.0f, ss = 0.0f;
    for (int r = r0 + h; r < r1; r += 2) {
        float v = t[(size_t)r * DD + c];
        s += v; ss += v * v;
    }
    sm[tid] = s; sq2[tid] = ss;
    __syncthreads();
    if (tid < 128) {
        PS[blockIdx.x * 128 + tid] = sm[tid] + sm[tid + 128];
        PQ[blockIdx.x * 128 + tid] = sq2[tid] + sq2[tid + 128];
    }
}

// ---- column stats stage 2 ----
__global__ void colstats_p2(const float* __restrict__ PS, const float* __restrict__ PQ,
                            float* __restrict__ sum, float* __restrict__ sumsq) {
    int t = threadIdx.x;  // 256
    float a = 0.0f;
    if (t < 128) {
        for (int b = 0; b < NBLK; ++b) a += PS[b * 128 + t];
        sum[t] = a;
    } else {
        int c = t - 128;
        for (int b = 0; b < NBLK; ++b) a += PQ[b * 128 + c];
        sumsq[c] = a;
    }
}

// ---- BN + ReLU, in place, float4 ----
__global__ __launch_bounds__(256) void bn_relu(
    float* __restrict__ h, int M, const float* __restrict__ sum, const float* __restrict__ sumsq,
    const float* __restrict__ gamma, const float* __restrict__ beta) {
    size_t i4 = (size_t)blockIdx.x * blockDim.x + threadIdx.x;
    size_t n4 = (size_t)M * 32;
    if (i4 >= n4) return;
    int c = (i4 & 31) * 4;
    float4 v = ((float4*)h)[i4];
    float inv[4], m[4], g[4], be[4];
#pragma unroll
    for (int j = 0; j < 4; ++j) {
        m[j] = sum[c + j] / (float)M;
        float var = fmaxf(sumsq[c + j] / (float)M - m[j] * m[j], 0.0f);
        inv[j] = rsqrtf(var + BN_EPS);
        g[j] = gamma[c + j]; be[j] = beta[c + j];
    }
    v.x = fmaxf(g[0] * (v.x - m[0]) * inv[0] + be[0], 0.0f);
    v.y = fmaxf(g[1] * (v.y - m[1]) * inv[1] + be[1], 0.0f);
    v.z = fmaxf(g[2] * (v.z - m[2]) * inv[2] + be[2], 0.0f);
    v.w = fmaxf(g[3] * (v.w - m[3]) * inv[3] + be[3], 0.0f);
    ((float4*)h)[i4] = v;
}

// ---- summary -> wsvec ----
__global__ void make_ws(const float* __restrict__ colsum, const float* __restrict__ discW,
                        float* __restrict__ wsv, int M) {
    __shared__ float s[128];
    int t = threadIdx.x;  // 128
    s[t] = 1.0f / (1.0f + expf(-(colsum[t] / (float)M)));
    __syncthreads();
    float acc = 0.0f;
    for (int j = 0; j < 128; ++j) acc += discW[t * 128 + j] * s[j];
    wsv[t] = acc;
}

// ---- loss stage 1 ----
__global__ __launch_bounds__(256) void loss_partial(
    const float* __restrict__ P, const float* __restrict__ Ng,
    const float* __restrict__ wsv, float* __restrict__ lossP, float* __restrict__ lossN, int M)
{
    __shared__ float sP[4], sN[4];
    int lane = threadIdx.x & 63;
    int wave = threadIdx.x >> 6;
    int gw = blockIdx.x * 4 + wave;
    int nw = gridDim.x * 4;
    float w0 = wsv[lane], w1 = wsv[lane + 64];
    float accP = 0.0f, accN = 0.0f;
    for (int row = gw; row < 2 * M; row += nw) {
        const float* base = (row < M) ? &P[(size_t)row * DD] : &Ng[(size_t)(row - M) * DD];
        float a = base[lane] * w0 + base[lane + 64] * w1;
#pragma unroll
        for (int off = 32; off > 0; off >>= 1) a += __shfl_down(a, off, 64);
        if (lane == 0) {
            float x = (row < M) ? -a : a;
            float sp = fmaxf(x, 0.0f) + log1pf(expf(-fabsf(x)));
            if (row < M) accP += sp; else accN += sp;
        }
    }
    if (lane == 0) { sP[wave] = accP; sN[wave] = accN; }
    __syncthreads();
    if (threadIdx.x == 0) {
        lossP[blockIdx.x] = sP[0] + sP[1] + sP[2] + sP[3];
        lossN[blockIdx.x] = sN[0] + sN[1] + sN[2] + sN[3];
    }
}

// ---- loss stage 2 ----
__global__ void write_loss(const float* __restrict__ lossP, const float* __restrict__ lossN,
                           void* __restrict__ outv, int M, const int* __restrict__ flagp) {
    __shared__ float s[256];
    int t = threadIdx.x;  // 256
    s[t] = (t < NBLK) ? (lossP[t] + lossN[t]) : 0.0f;
    __syncthreads();
    for (int off = 128; off > 0; off >>= 1) { if (t < off) s[t] += s[t + off]; __syncthreads(); }
    if (t == 0) {
        float v = s[0] / (float)M;
        if (*flagp) ((bf16*)outv)[20000] = __float2bfloat16(v);
        else        ((float*)outv)[20000] = v;
    }
}

// ---- predictor input ----
__global__ __launch_bounds__(256) void pair_mult(
    const float* __restrict__ P, const int* __restrict__ s_idx, const int* __restrict__ d_idx,
    float* __restrict__ Z, int nPair) {
    int i = blockIdx.x * 2 + (threadIdx.x >> 7);
    int f = threadIdx.x & 127;
    if (i >= nPair) return;
    Z[(size_t)i * DD + f] = P[(size_t)s_idx[i] * DD + f] * P[(size_t)d_idx[i] * DD + f];
}

// ---- final 128 -> 1 matvec ----
__global__ __launch_bounds__(256) void final_mv(
    const float* __restrict__ ZB, const float* __restrict__ pW3, const float* __restrict__ pb3,
    void* __restrict__ outv, int nRows, int outOff, const int* __restrict__ flagp) {
    int row = blockIdx.x * 4 + (threadIdx.x >> 6);
    int lane = threadIdx.x & 63;
    if (row >= nRows) return;
    float a = ZB[(size_t)row * DD + lane] * pW3[lane]
            + ZB[(size_t)row * DD + lane + 64] * pW3[lane + 64];
#pragma unroll
    for (int off = 32; off > 0; off >>= 1) a += __shfl_down(a, off, 64);
    if (lane == 0) {
        float v = a + pb3[0];
        if (*flagp) ((bf16*)outv)[outOff + row] = __float2bfloat16(v);
        else        ((float*)outv)[outOff + row] = v;
    }
}

extern "C" void kernel_launch(void* const* d_in, const int* in_sizes, int n_in,
                              void* d_out, int out_size, void* d_ws, size_t ws_size,
                              hipStream_t stream)
{
    const void* x      = d_in[0];
    const int* srcA[3] = {(const int*)d_in[1], (const int*)d_in[3], (const int*)d_in[5]};
    const int* dstA[3] = {(const int*)d_in[2], (const int*)d_in[4], (const int*)d_in[6]};
    const int* perm    = (const int*)d_in[7];
    const int* pos_src = (const int*)d_in[8];
    const int* pos_dst = (const int*)d_in[9];
    const int* neg_src = (const int*)d_in[10];
    const int* neg_dst = (const int*)d_in[11];

    const int N1 = 50000, N2 = 25000, N3 = 12500;
    const int E[3] = {750000, 250000, 125000};
    const int EP = 10000;

    // ---- ws layout (4-byte units) ----
    float* wsf = (float*)d_ws;
    int*   wsi = (int*)d_ws;
    int*   flagp = wsi;
    float* PS    = wsf + 256;
    float* PQ    = wsf + 20736;
    float* lossP = wsf + 41216;
    float* lossN = wsf + 41376;
    float* sumS  = wsf + 41600;
    float* sqS   = wsf + 41728;
    float* wsvec = wsf + 41856;
    int* hist0 = wsi + 43008;
    int* hist1 = wsi + 93008;
    int* hist2 = wsi + 118008;
    int* cur0  = wsi + 130560;
    int* cur1  = wsi + 180560;
    int* cur2  = wsi + 205560;
    int* rp0   = wsi + 218112;
    int* rp1   = wsi + 268160;
    int* rp2   = wsi + 293248;
    int* eid0  = wsi + 305792;
    int* eid1  = wsi + 1055792;
    int* eid2  = wsi + 1305792;
    const size_t WfB = 1431040;
    float* WS[3] = {wsf + WfB +      0, wsf + WfB +  32896, wsf + WfB +  65792};
    float* WN[3] = {wsf + WfB +  16384, wsf + WfB +  49280, wsf + WfB +  82176};
    float* BV[3] = {wsf + WfB +  32768, wsf + WfB +  65664, wsf + WfB +  98560};
    float* G0  = wsf + WfB +  98688; float* BE0 = wsf + WfB +  98816;
    float* G1  = wsf + WfB +  98944; float* BE1 = wsf + WfB +  99072;
    float* DW  = wsf + WfB +  99200;
    float* PW1 = wsf + WfB + 115584; float* PB1 = wsf + WfB + 131968;
    float* PW2 = wsf + WfB + 132096; float* PB2 = wsf + WfB + 148480;
    float* PW3 = wsf + WfB + 148608; float* PB3 = wsf + WfB + 148736;
    float* PF  = wsf + 1580032;                   // 1,600,000
    float* NF  = wsf + 3180032;                   // 1,600,000
    float* H2  = wsf + 4780032;                   // 3,200,000
    float* H1  = wsf + 7980032;                   // 6,400,000
    float* AGG = wsf + 14380032;                  // up to 6,400,000
    float* Z  = H1;
    float* ZA = H1 + 1280000;
    float* ZB = H1 + 2560000;

    // AGG rows: 50000 (single L0 chunk) if ws permits, else 25000 (constant per process)
    int aggRows = (ws_size >= (size_t)(14380032 + 6400000) * 4) ? 50000 : 25000;

    // ---- dtype detect + fused weight conversion ----
    detect_dtype<<<1, 256, 0, stream>>>((const unsigned int*)x, flagp);
    CvtTable tab;
    const int widx[20] = {12,13,14, 15,16,17, 18,19,20, 21,22,23,24, 25, 26,27, 28,29, 30,31};
    float* wdst[20] = {WS[0],WN[0],BV[0], WS[1],WN[1],BV[1], WS[2],WN[2],BV[2],
                       G0,BE0,G1,BE1, DW, PW1,PB1, PW2,PB2, PW3,PB3};
    const int wn[20] = {16384,16384,128, 16384,16384,128, 16384,16384,128,
                        128,128,128,128, 16384, 16384,128, 16384,128, 128,1};
    int tot = 0;
    for (int k = 0; k < 20; ++k) {
        tab.src[k] = d_in[widx[k]];
        tab.off[k] = (int)(wdst[k] - wsf);
        tab.n[k] = wn[k];
        tot += wn[k];
    }
    tab.total = tot;
    cvt_all<<<(tot + 255) / 256, 256, 0, stream>>>(tab, wsf, flagp);

    // ---- CSR build (shared by both passes) ----
    hipMemsetAsync(hist0, 0, (size_t)(218060 - 43008) * 4, stream);  // hist+cursor
    int* histA[3] = {hist0, hist1, hist2};
    int* curA[3]  = {cur0, cur1, cur2};
    int* rpA[3]   = {rp0, rp1, rp2};
    int* eidA[3]  = {eid0, eid1, eid2};
    const int NdA[3] = {N1, N2, N3};
    for (int l = 0; l < 3; ++l) {
        hist_count<<<(E[l] + 255) / 256, 256, 0, stream>>>(dstA[l], E[l], histA[l]);
        exscan<<<1, 256, 0, stream>>>(histA[l], NdA[l], rpA[l]);
        csr_fill<<<(E[l] + 255) / 256, 256, 0, stream>>>(srcA[l], dstA[l], E[l],
                                                         rpA[l], curA[l], eidA[l]);
    }

    for (int pass = 0; pass < 2; ++pass) {
        const int* g = (pass == 0) ? nullptr : perm;
        float* OUT = (pass == 0) ? PF : NF;

        // ===== layer 0 (M=50000): gather + fused self/neigh gemm per chunk =====
        for (int lo = 0; lo < N1; lo += aggRows) {
            int ch = min(aggRows, N1 - lo);
            gather_mean<<<(ch + 3) / 4, 256, 0, stream>>>(
                x, flagp, g, rp0, eid0, lo, lo + ch, AGG);
            gemm256<<<(ch + 31) / 32, 256, 0, stream>>>(
                x, flagp, g, lo, AGG, WS[0], WN[0], BV[0], H1, ch, 0);
        }
        colstats_p1<<<NBLK, 256, 0, stream>>>(H1, N1, PS, PQ);
        colstats_p2<<<1, 256, 0, stream>>>(PS, PQ, sumS, sqS);
        bn_relu<<<((size_t)N1 * 32 + 255) / 256, 256, 0, stream>>>(H1, N1, sumS, sqS, G0, BE0);

        // ===== layer 1 (M=25000) =====
        gather_mean<<<(N2 + 3) / 4, 256, 0, stream>>>(
            H1, nullptr, nullptr, rp1, eid1, 0, N2, AGG);
        gemm256<<<(N2 + 31) / 32, 256, 0, stream>>>(
            H1, nullptr, nullptr, 0, AGG, WS[1], WN[1], BV[1], H2, N2, 0);
        colstats_p1<<<NBLK, 256, 0, stream>>>(H2, N2, PS, PQ);
        colstats_p2<<<1, 256, 0, stream>>>(PS, PQ, sumS, sqS);
        bn_relu<<<((size_t)N2 * 32 + 255) / 256, 256, 0, stream>>>(H2, N2, sumS, sqS, G1, BE1);

        // ===== layer 2 (M=12500), no BN =====
        gather_mean<<<(N3 + 3) / 4, 256, 0, stream>>>(
            H2, nullptr, nullptr, rp2, eid2, 0, N3, AGG);
        gemm256<<<(N3 + 31) / 32, 256, 0, stream>>>(
            H2, nullptr, nullptr, 0, AGG, WS[2], WN[2], BV[2], OUT, N3, 0);
    }

    // ---- summary / discriminator loss ----
    colstats_p1<<<NBLK, 256, 0, stream>>>(PF, N3, PS, PQ);
    colstats_p2<<<1, 256, 0, stream>>>(PS, PQ, sumS, sqS);
    make_ws<<<1, 128, 0, stream>>>(sumS, DW, wsvec, N3);
    loss_partial<<<NBLK, 256, 0, stream>>>(PF, NF, wsvec, lossP, lossN, N3);
    write_loss<<<1, 256, 0, stream>>>(lossP, lossN, d_out, N3, flagp);

    // ---- predictor MLP: pos pairs then neg pairs ----
    for (int c = 0; c < 2; ++c) {
        const int* si = (c == 0) ? pos_src : neg_src;
        const int* di = (c == 0) ? pos_dst : neg_dst;
        pair_mult<<<(EP + 1) / 2, 256, 0, stream>>>(PF, si, di, Z, EP);
        gemm128<<<(EP + 31) / 32, 256, 0, stream>>>(Z,  PW1, PB1, ZA, EP, 1);
        gemm128<<<(EP + 31) / 32, 256, 0, stream>>>(ZA, PW2, PB2, ZB, EP, 1);
        final_mv<<<(EP + 3) / 4, 256, 0, stream>>>(ZB, PW3, PB3, d_out, EP, c * EP, flagp);
    }
}

// Round 9
// 1023.001 us; speedup vs baseline: 3.0209x; 1.1277x over previous
//
#include <hip/hip_runtime.h>
#include <hip/hip_bf16.h>

#define DD 128
#define BN_EPS 1e-5f
#define NBLK 160   // blocks for stats/loss partial kernels

typedef __hip_bfloat16 bf16;

__device__ __forceinline__ float b2f(unsigned short u) {
    union { float f; unsigned int i; } x; x.i = ((unsigned int)u) << 16; return x.f;
}

// ---- dtype detect: flag=1 if d_in[0] is packed bf16, 0 if f32 ----
__global__ void detect_dtype(const unsigned int* __restrict__ x, int* __restrict__ flag) {
    __shared__ int s[256];
    int t = threadIdx.x;
    unsigned int u = x[t];
    unsigned int e = (u >> 7) & 0xFFu;
    s[t] = ((e >= 90u && e <= 140u) || ((u & 0xFFFFu) == 0u)) ? 1 : 0;
    __syncthreads();
    for (int off = 128; off > 0; off >>= 1) { if (t < off) s[t] += s[t + off]; __syncthreads(); }
    if (t == 0) *flag = (s[0] >= 128) ? 1 : 0;
}

// ---- fused weight conversion ----
struct CvtTable {
    const void* src[20];
    int off[20];
    int n[20];
    int total;
};
__global__ __launch_bounds__(256) void cvt_all(CvtTable tab, float* __restrict__ wsf,
                                               const int* __restrict__ flagp) {
    int i = blockIdx.x * 256 + threadIdx.x;
    if (i >= tab.total) return;
    int k = 0;
    while (i >= tab.n[k]) { i -= tab.n[k]; ++k; }
    float v;
    if (*flagp) v = b2f(((const unsigned short*)tab.src[k])[i]);
    else        v = ((const float*)tab.src[k])[i];
    wsf[tab.off[k] + i] = v;
}

// ---- CSR build: fused histogram over all 3 layers ----
__global__ __launch_bounds__(256) void hist_all(
    const int* __restrict__ d0, int e0, const int* __restrict__ d1, int e1,
    const int* __restrict__ d2, int e2,
    int* __restrict__ h0, int* __restrict__ h1, int* __restrict__ h2) {
    int e = blockIdx.x * 256 + threadIdx.x;
    if (e < e0) atomicAdd(&h0[d0[e]], 1);
    else if (e < e0 + e1) atomicAdd(&h1[d1[e - e0]], 1);
    else if (e < e0 + e1 + e2) atomicAdd(&h2[d2[e - e0 - e1]], 1);
}

// ---- hierarchical exclusive scan (n % 4 == 0, int4 path) ----
// stage 1: per-block sums (1024 elems / block)
__global__ __launch_bounds__(256) void scan_bsum(const int* __restrict__ cnt, int n,
                                                 int* __restrict__ bsums) {
    __shared__ int sm[256];
    int t = threadIdx.x, b = blockIdx.x;
    int i4 = b * 256 + t;
    int local = 0;
    if (i4 * 4 < n) { int4 v = ((const int4*)cnt)[i4]; local = v.x + v.y + v.z + v.w; }
    sm[t] = local;
    __syncthreads();
    for (int off = 128; off > 0; off >>= 1) { if (t < off) sm[t] += sm[t + off]; __syncthreads(); }
    if (t == 0) bsums[b] = sm[0];
}
// stage 2: exclusive scan of block sums (nb <= 256), write total to rowptr[n]
__global__ void scan_bscan(int* __restrict__ bsums, int nb, int* __restrict__ rowptr_n) {
    __shared__ int wsum[4];
    int t = threadIdx.x, lane = t & 63, w = t >> 6;
    int v = (t < nb) ? bsums[t] : 0;
    int inc = v;
    for (int off = 1; off < 64; off <<= 1) {
        int u = __shfl_up(inc, off, 64);
        if (lane >= off) inc += u;
    }
    if (lane == 63) wsum[w] = inc;
    __syncthreads();
    int wo = 0;
    for (int i = 0; i < w; ++i) wo += wsum[i];
    if (t < nb) bsums[t] = wo + inc - v;
    if (t == 255) *rowptr_n = wo + inc;
}
// stage 3: apply offsets, write rowptr[0..n)
__global__ __launch_bounds__(256) void scan_apply(const int* __restrict__ cnt, int n,
                                                  const int* __restrict__ bsums,
                                                  int* __restrict__ rowptr) {
    __shared__ int wsum[4];
    int t = threadIdx.x, b = blockIdx.x, lane = t & 63, w = t >> 6;
    int i4 = b * 256 + t;
    int4 v = {0, 0, 0, 0};
    bool valid = (i4 * 4 < n);
    if (valid) v = ((const int4*)cnt)[i4];
    int local = v.x + v.y + v.z + v.w;
    int inc = local;
    for (int off = 1; off < 64; off <<= 1) {
        int u = __shfl_up(inc, off, 64);
        if (lane >= off) inc += u;
    }
    if (lane == 63) wsum[w] = inc;
    __syncthreads();
    int wo = 0;
    for (int i = 0; i < w; ++i) wo += wsum[i];
    if (valid) {
        int acc = bsums[b] + wo + inc - local;
        int base = i4 * 4;
        rowptr[base + 0] = acc; acc += v.x;
        rowptr[base + 1] = acc; acc += v.y;
        rowptr[base + 2] = acc; acc += v.z;
        rowptr[base + 3] = acc;
    }
}

// ---- CSR fill: fused over all 3 layers ----
__global__ __launch_bounds__(256) void csr_fill_all(
    const int* __restrict__ s0, const int* __restrict__ d0, int e0,
    const int* __restrict__ s1, const int* __restrict__ d1, int e1,
    const int* __restrict__ s2, const int* __restrict__ d2, int e2,
    const int* __restrict__ rp0, int* __restrict__ cu0, int* __restrict__ ei0,
    const int* __restrict__ rp1, int* __restrict__ cu1, int* __restrict__ ei1,
    const int* __restrict__ rp2, int* __restrict__ cu2, int* __restrict__ ei2) {
    int e = blockIdx.x * 256 + threadIdx.x;
    if (e < e0) {
        int d = d0[e];
        ei0[rp0[d] + atomicAdd(&cu0[d], 1)] = s0[e];
    } else if (e < e0 + e1) {
        int i = e - e0, d = d1[i];
        ei1[rp1[d] + atomicAdd(&cu1[d], 1)] = s1[i];
    } else if (e < e0 + e1 + e2) {
        int i = e - e0 - e1, d = d2[i];
        ei2[rp2[d] + atomicAdd(&cu2[d], 1)] = s2[i];
    }
}

// ---- CSR gather: one wave per dst row, lane covers 2 features, 4-deep unroll ----
__global__ __launch_bounds__(256) void gather_mean(
    const void* __restrict__ hv, const int* __restrict__ flagp, const int* __restrict__ perm,
    const int* __restrict__ rowptr, const int* __restrict__ eid,
    int lo, int hi, float* __restrict__ out)
{
    int d = lo + blockIdx.x * 4 + (threadIdx.x >> 6);
    int lane = threadIdx.x & 63;
    if (d >= hi) return;
    int i0 = rowptr[d], i1 = rowptr[d + 1];
    int abf = flagp ? *flagp : 0;
    float a0x = 0, a0y = 0, a1x = 0, a1y = 0, a2x = 0, a2y = 0, a3x = 0, a3y = 0;
    int i = i0;
    if (abf) {
        const unsigned short* h = (const unsigned short*)hv;
        for (; i + 4 <= i1; i += 4) {
            int s0 = eid[i], s1 = eid[i + 1], s2 = eid[i + 2], s3 = eid[i + 3];
            if (perm) { s0 = perm[s0]; s1 = perm[s1]; s2 = perm[s2]; s3 = perm[s3]; }
            ushort2 v0 = *(const ushort2*)&h[(size_t)s0 * DD + lane * 2];
            ushort2 v1 = *(const ushort2*)&h[(size_t)s1 * DD + lane * 2];
            ushort2 v2 = *(const ushort2*)&h[(size_t)s2 * DD + lane * 2];
            ushort2 v3 = *(const ushort2*)&h[(size_t)s3 * DD + lane * 2];
            a0x += b2f(v0.x); a0y += b2f(v0.y);
            a1x += b2f(v1.x); a1y += b2f(v1.y);
            a2x += b2f(v2.x); a2y += b2f(v2.y);
            a3x += b2f(v3.x); a3y += b2f(v3.y);
        }
        for (; i < i1; ++i) {
            int s = eid[i];
            if (perm) s = perm[s];
            ushort2 v = *(const ushort2*)&h[(size_t)s * DD + lane * 2];
            a0x += b2f(v.x); a0y += b2f(v.y);
        }
    } else {
        const float* h = (const float*)hv;
        for (; i + 4 <= i1; i += 4) {
            int s0 = eid[i], s1 = eid[i + 1], s2 = eid[i + 2], s3 = eid[i + 3];
            if (perm) { s0 = perm[s0]; s1 = perm[s1]; s2 = perm[s2]; s3 = perm[s3]; }
            float2 v0 = *(const float2*)&h[(size_t)s0 * DD + lane * 2];
            float2 v1 = *(const float2*)&h[(size_t)s1 * DD + lane * 2];
            float2 v2 = *(const float2*)&h[(size_t)s2 * DD + lane * 2];
            float2 v3 = *(const float2*)&h[(size_t)s3 * DD + lane * 2];
            a0x += v0.x; a0y += v0.y;
            a1x += v1.x; a1y += v1.y;
            a2x += v2.x; a2y += v2.y;
            a3x += v3.x; a3y += v3.y;
        }
        for (; i < i1; ++i) {
            int s = eid[i];
            if (perm) s = perm[s];
            float2 v = *(const float2*)&h[(size_t)s * DD + lane * 2];
            a0x += v.x; a0y += v.y;
        }
    }
    float rd = 1.0f / fmaxf((float)(i1 - i0), 1.0f);
    float2 o;
    o.x = (a0x + a1x + a2x + a3x) * rd;
    o.y = (a0y + a1y + a2y + a3y) * rd;
    *(float2*)&out[(size_t)(d - lo) * DD + lane * 2] = o;
}

// ---- fused SAGE GEMM: out[lo+r] = A1[g(lo+r)] @ W1 + A2[r] @ W2 + bias, K=256 ----
__global__ __launch_bounds__(256) void gemm256(
    const void* __restrict__ A1v, const int* __restrict__ flagp,
    const int* __restrict__ gather, int lo,
    const float* __restrict__ A2,
    const float* __restrict__ W1, const float* __restrict__ W2,
    const float* __restrict__ bias,
    float* __restrict__ out, int Mc, int relu)
{
    __shared__ float As1[32][129];
    __shared__ float As2[32][129];
    __shared__ float Wsm[32 * DD];
    const int tid = threadIdx.x;
    const int rb = blockIdx.x * 32;
    const int abf = flagp ? *flagp : 0;

    {
        int r = tid >> 3, c0 = (tid & 7) * 16;
        int lr = rb + r;
        if (lr < Mc) {
            int ar = gather ? gather[lo + lr] : (lo + lr);
            size_t b1 = (size_t)ar * DD + c0;
            if (abf) {
                const unsigned short* Ab = (const unsigned short*)A1v;
#pragma unroll
                for (int j = 0; j < 16; ++j) As1[r][c0 + j] = b2f(Ab[b1 + j]);
            } else {
                const float* Af = (const float*)A1v;
#pragma unroll
                for (int j = 0; j < 16; ++j) As1[r][c0 + j] = Af[b1 + j];
            }
            const float* a2 = A2 + (size_t)lr * DD + c0;
#pragma unroll
            for (int j = 0; j < 16; ++j) As2[r][c0 + j] = a2[j];
        } else {
#pragma unroll
            for (int j = 0; j < 16; ++j) { As1[r][c0 + j] = 0.0f; As2[r][c0 + j] = 0.0f; }
        }
    }

    const int tx = tid & 31, ty = tid >> 5;
    const int c = tx * 4;
    float acc[4][4] = {};

#pragma unroll
    for (int ph = 0; ph < 8; ++ph) {
        __syncthreads();
        const float* W = (ph < 4) ? W1 : W2;
        const int q = ph & 3;
        {
            const float4* wsrc = (const float4*)(W + q * 32 * DD);
            float4* wdst = (float4*)Wsm;
#pragma unroll
            for (int i = 0; i < 4; ++i) wdst[i * 256 + tid] = wsrc[i * 256 + tid];
        }
        __syncthreads();
        float (*As)[129] = (ph < 4) ? As1 : As2;
#pragma unroll 2
        for (int k2 = 0; k2 < 32; ++k2) {
            float4 wv = *(const float4*)&Wsm[k2 * DD + c];
            int k = q * 32 + k2;
            float a[4] = { As[ty][k], As[ty + 8][k], As[ty + 16][k], As[ty + 24][k] };
            float w[4] = { wv.x, wv.y, wv.z, wv.w };
#pragma unroll
            for (int i = 0; i < 4; ++i)
#pragma unroll
                for (int j = 0; j < 4; ++j) acc[i][j] = fmaf(a[i], w[j], acc[i][j]);
        }
    }

#pragma unroll
    for (int i = 0; i < 4; ++i) {
        int r = rb + ty + 8 * i;
        if (r >= Mc) continue;
        float* orow = out + (size_t)(lo + r) * DD + c;
#pragma unroll
        for (int j = 0; j < 4; ++j) {
            float v = acc[i][j] + bias[c + j];
            if (relu) v = fmaxf(v, 0.0f);
            orow[j] = v;
        }
    }
}

// ---- plain [M x 128] @ [128 x 128] GEMM (predictor MLP) ----
__global__ __launch_bounds__(256) void gemm128(
    const float* __restrict__ A,
    const float* __restrict__ W, const float* __restrict__ bias,
    float* __restrict__ out, int M, int relu)
{
    __shared__ float As[32][129];
    __shared__ float Wsm[64 * DD];
    const int tid = threadIdx.x;
    const int rb = blockIdx.x * 32;

    {
        int r = tid >> 3, c0 = (tid & 7) * 16;
        int gr = rb + r;
        if (gr < M) {
            const float* arow = A + (size_t)gr * DD + c0;
#pragma unroll
            for (int j = 0; j < 16; ++j) As[r][c0 + j] = arow[j];
        } else {
#pragma unroll
            for (int j = 0; j < 16; ++j) As[r][c0 + j] = 0.0f;
        }
    }

    const int tx = tid & 31, ty = tid >> 5;
    const int c = tx * 4;
    float acc[4][4] = {};

#pragma unroll
    for (int half = 0; half < 2; ++half) {
        __syncthreads();
        {
            const float4* wsrc = (const float4*)(W + half * 64 * DD);
            float4* wdst = (float4*)Wsm;
#pragma unroll
            for (int i = 0; i < 8; ++i) wdst[i * 256 + tid] = wsrc[i * 256 + tid];
        }
        __syncthreads();
#pragma unroll 2
        for (int k2 = 0; k2 < 64; ++k2) {
            float4 wv = *(const float4*)&Wsm[k2 * DD + c];
            int k = half * 64 + k2;
            float a[4] = { As[ty][k], As[ty + 8][k], As[ty + 16][k], As[ty + 24][k] };
            float w[4] = { wv.x, wv.y, wv.z, wv.w };
#pragma unroll
            for (int i = 0; i < 4; ++i)
#pragma unroll
                for (int j = 0; j < 4; ++j) acc[i][j] = fmaf(a[i], w[j], acc[i][j]);
        }
    }

#pragma unroll
    for (int i = 0; i < 4; ++i) {
        int r = rb + ty + 8 * i;
        if (r >= M) continue;
        float* orow = out + (size_t)r * DD + c;
#pragma unroll
        for (int j = 0; j < 4; ++j) {
            float v = acc[i][j] + bias[c + j];
            if (relu) v = fmaxf(v, 0.0f);
            orow[j] = v;
        }
    }
}

// ---- column stats stage 1 ----
__global__ __launch_bounds__(256) void colstats_p1(
    const float* __restrict__ t, int M,
    float* __restrict__ PS, float* __restrict__ PQ)
{
    __shared__ float sm[256], sq2[256];
    int tid = threadIdx.x;
    int c = tid & 127, h = tid >> 7;
    int rpb = (M + NBLK - 1) / NBLK;
    int r0 = blockIdx.x * rpb;
    int r1 = min(r0 + rpb, M);
    float s = 0.0f, ss = 0.0f;
    for (int r = r0 + h; r < r1; r += 2) {
        float v = t[(size_t)r * DD + c];
        s += v; ss += v * v;
    }
    sm[tid] = s; sq2[tid] = ss;
    __syncthreads();
    if (tid < 128) {
        PS[blockIdx.x * 128 + tid] = sm[tid] + sm[tid + 128];
        PQ[blockIdx.x * 128 + tid] = sq2[tid] + sq2[tid + 128];
    }
}

// ---- column stats stage 2 ----
__global__ void colstats_p2(const float* __restrict__ PS, const float* __restrict__ PQ,
                            float* __restrict__ sum, float* __restrict__ sumsq) {
    int t = threadIdx.x;  // 256
    float a = 0.0f;
    if (t < 128) {
        for (int b = 0; b < NBLK; ++b) a += PS[b * 128 + t];
        sum[t] = a;
    } else {
        int c = t - 128;
        for (int b = 0; b < NBLK; ++b) a += PQ[b * 128 + c];
        sumsq[c] = a;
    }
}

// ---- BN + ReLU, in place, float4 ----
__global__ __launch_bounds__(256) void bn_relu(
    float* __restrict__ h, int M, const float* __restrict__ sum, const float* __restrict__ sumsq,
    const float* __restrict__ gamma, const float* __restrict__ beta) {
    size_t i4 = (size_t)blockIdx.x * blockDim.x + threadIdx.x;
    size_t n4 = (size_t)M * 32;
    if (i4 >= n4) return;
    int c = (i4 & 31) * 4;
    float4 v = ((float4*)h)[i4];
    float inv[4], m[4], g[4], be[4];
#pragma unroll
    for (int j = 0; j < 4; ++j) {
        m[j] = sum[c + j] / (float)M;
        float var = fmaxf(sumsq[c + j] / (float)M - m[j] * m[j], 0.0f);
        inv[j] = rsqrtf(var + BN_EPS);
        g[j] = gamma[c + j]; be[j] = beta[c + j];
    }
    v.x = fmaxf(g[0] * (v.x - m[0]) * inv[0] + be[0], 0.0f);
    v.y = fmaxf(g[1] * (v.y - m[1]) * inv[1] + be[1], 0.0f);
    v.z = fmaxf(g[2] * (v.z - m[2]) * inv[2] + be[2], 0.0f);
    v.w = fmaxf(g[3] * (v.w - m[3]) * inv[3] + be[3], 0.0f);
    ((float4*)h)[i4] = v;
}

// ---- summary -> wsvec ----
__global__ void make_ws(const float* __restrict__ colsum, const float* __restrict__ discW,
                        float* __restrict__ wsv, int M) {
    __shared__ float s[128];
    int t = threadIdx.x;  // 128
    s[t] = 1.0f / (1.0f + expf(-(colsum[t] / (float)M)));
    __syncthreads();
    float acc = 0.0f;
    for (int j = 0; j < 128; ++j) acc += discW[t * 128 + j] * s[j];
    wsv[t] = acc;
}

// ---- loss stage 1 ----
__global__ __launch_bounds__(256) void loss_partial(
    const float* __restrict__ P, const float* __restrict__ Ng,
    const float* __restrict__ wsv, float* __restrict__ lossP, float* __restrict__ lossN, int M)
{
    __shared__ float sP[4], sN[4];
    int lane = threadIdx.x & 63;
    int wave = threadIdx.x >> 6;
    int gw = blockIdx.x * 4 + wave;
    int nw = gridDim.x * 4;
    float w0 = wsv[lane], w1 = wsv[lane + 64];
    float accP = 0.0f, accN = 0.0f;
    for (int row = gw; row < 2 * M; row += nw) {
        const float* base = (row < M) ? &P[(size_t)row * DD] : &Ng[(size_t)(row - M) * DD];
        float a = base[lane] * w0 + base[lane + 64] * w1;
#pragma unroll
        for (int off = 32; off > 0; off >>= 1) a += __shfl_down(a, off, 64);
        if (lane == 0) {
            float x = (row < M) ? -a : a;
            float sp = fmaxf(x, 0.0f) + log1pf(expf(-fabsf(x)));
            if (row < M) accP += sp; else accN += sp;
        }
    }
    if (lane == 0) { sP[wave] = accP; sN[wave] = accN; }
    __syncthreads();
    if (threadIdx.x == 0) {
        lossP[blockIdx.x] = sP[0] + sP[1] + sP[2] + sP[3];
        lossN[blockIdx.x] = sN[0] + sN[1] + sN[2] + sN[3];
    }
}

// ---- loss stage 2 ----
__global__ void write_loss(const float* __restrict__ lossP, const float* __restrict__ lossN,
                           void* __restrict__ outv, int M, const int* __restrict__ flagp) {
    __shared__ float s[256];
    int t = threadIdx.x;  // 256
    s[t] = (t < NBLK) ? (lossP[t] + lossN[t]) : 0.0f;
    __syncthreads();
    for (int off = 128; off > 0; off >>= 1) { if (t < off) s[t] += s[t + off]; __syncthreads(); }
    if (t == 0) {
        float v = s[0] / (float)M;
        if (*flagp) ((bf16*)outv)[20000] = __float2bfloat16(v);
        else        ((float*)outv)[20000] = v;
    }
}

// ---- predictor input ----
__global__ __launch_bounds__(256) void pair_mult(
    const float* __restrict__ P, const int* __restrict__ s_idx, const int* __restrict__ d_idx,
    float* __restrict__ Z, int nPair) {
    int i = blockIdx.x * 2 + (threadIdx.x >> 7);
    int f = threadIdx.x & 127;
    if (i >= nPair) return;
    Z[(size_t)i * DD + f] = P[(size_t)s_idx[i] * DD + f] * P[(size_t)d_idx[i] * DD + f];
}

// ---- final 128 -> 1 matvec ----
__global__ __launch_bounds__(256) void final_mv(
    const float* __restrict__ ZB, const float* __restrict__ pW3, const float* __restrict__ pb3,
    void* __restrict__ outv, int nRows, int outOff, const int* __restrict__ flagp) {
    int row = blockIdx.x * 4 + (threadIdx.x >> 6);
    int lane = threadIdx.x & 63;
    if (row >= nRows) return;
    float a = ZB[(size_t)row * DD + lane] * pW3[lane]
            + ZB[(size_t)row * DD + lane + 64] * pW3[lane + 64];
#pragma unroll
    for (int off = 32; off > 0; off >>= 1) a += __shfl_down(a, off, 64);
    if (lane == 0) {
        float v = a + pb3[0];
        if (*flagp) ((bf16*)outv)[outOff + row] = __float2bfloat16(v);
        else        ((float*)outv)[outOff + row] = v;
    }
}

extern "C" void kernel_launch(void* const* d_in, const int* in_sizes, int n_in,
                              void* d_out, int out_size, void* d_ws, size_t ws_size,
                              hipStream_t stream)
{
    const void* x      = d_in[0];
    const int* srcA[3] = {(const int*)d_in[1], (const int*)d_in[3], (const int*)d_in[5]};
    const int* dstA[3] = {(const int*)d_in[2], (const int*)d_in[4], (const int*)d_in[6]};
    const int* perm    = (const int*)d_in[7];
    const int* pos_src = (const int*)d_in[8];
    const int* pos_dst = (const int*)d_in[9];
    const int* neg_src = (const int*)d_in[10];
    const int* neg_dst = (const int*)d_in[11];

    const int N1 = 50000, N2 = 25000, N3 = 12500;
    const int E[3] = {750000, 250000, 125000};
    const int EP = 10000;

    // ---- ws layout (4-byte units) ----
    float* wsf = (float*)d_ws;
    int*   wsi = (int*)d_ws;
    int*   flagp = wsi;
    float* PS    = wsf + 256;
    float* PQ    = wsf + 20736;
    float* lossP = wsf + 41216;
    float* lossN = wsf + 41376;
    float* sumS  = wsf + 41600;
    float* sqS   = wsf + 41728;
    float* wsvec = wsf + 41856;
    int*   bsums = wsi + 41984;                   // 256 scan scratch
    int* hist0 = wsi + 43008;
    int* hist1 = wsi + 93008;
    int* hist2 = wsi + 118008;
    int* cur0  = wsi + 130560;
    int* cur1  = wsi + 180560;
    int* cur2  = wsi + 205560;
    int* rp0   = wsi + 218112;
    int* rp1   = wsi + 268160;
    int* rp2   = wsi + 293248;
    int* eid0  = wsi + 305792;
    int* eid1  = wsi + 1055792;
    int* eid2  = wsi + 1305792;
    const size_t WfB = 1431040;
    float* WS[3] = {wsf + WfB +      0, wsf + WfB +  32896, wsf + WfB +  65792};
    float* WN[3] = {wsf + WfB +  16384, wsf + WfB +  49280, wsf + WfB +  82176};
    float* BV[3] = {wsf + WfB +  32768, wsf + WfB +  65664, wsf + WfB +  98560};
    float* G0  = wsf + WfB +  98688; float* BE0 = wsf + WfB +  98816;
    float* G1  = wsf + WfB +  98944; float* BE1 = wsf + WfB +  99072;
    float* DW  = wsf + WfB +  99200;
    float* PW1 = wsf + WfB + 115584; float* PB1 = wsf + WfB + 131968;
    float* PW2 = wsf + WfB + 132096; float* PB2 = wsf + WfB + 148480;
    float* PW3 = wsf + WfB + 148608; float* PB3 = wsf + WfB + 148736;
    float* PF  = wsf + 1580032;                   // 1,600,000
    float* NF  = wsf + 3180032;                   // 1,600,000
    float* H2  = wsf + 4780032;                   // 3,200,000
    float* H1  = wsf + 7980032;                   // 6,400,000
    float* AGG = wsf + 14380032;                  // up to 6,400,000
    float* Z  = H1;
    float* ZA = H1 + 1280000;
    float* ZB = H1 + 2560000;

    // AGG rows: 50000 (single L0 chunk) if ws permits, else 25000 (constant per process)
    int aggRows = (ws_size >= (size_t)(14380032 + 6400000) * 4) ? 50000 : 25000;

    // ---- dtype detect + fused weight conversion ----
    detect_dtype<<<1, 256, 0, stream>>>((const unsigned int*)x, flagp);
    CvtTable tab;
    const int widx[20] = {12,13,14, 15,16,17, 18,19,20, 21,22,23,24, 25, 26,27, 28,29, 30,31};
    float* wdst[20] = {WS[0],WN[0],BV[0], WS[1],WN[1],BV[1], WS[2],WN[2],BV[2],
                       G0,BE0,G1,BE1, DW, PW1,PB1, PW2,PB2, PW3,PB3};
    const int wn[20] = {16384,16384,128, 16384,16384,128, 16384,16384,128,
                        128,128,128,128, 16384, 16384,128, 16384,128, 128,1};
    int tot = 0;
    for (int k = 0; k < 20; ++k) {
        tab.src[k] = d_in[widx[k]];
        tab.off[k] = (int)(wdst[k] - wsf);
        tab.n[k] = wn[k];
        tot += wn[k];
    }
    tab.total = tot;
    cvt_all<<<(tot + 255) / 256, 256, 0, stream>>>(tab, wsf, flagp);

    // ---- CSR build (shared by both passes) ----
    hipMemsetAsync(hist0, 0, (size_t)(218060 - 43008) * 4, stream);  // hist + cursor
    int Etot = E[0] + E[1] + E[2];
    hist_all<<<(Etot + 255) / 256, 256, 0, stream>>>(
        dstA[0], E[0], dstA[1], E[1], dstA[2], E[2], hist0, hist1, hist2);
    int* histA[3] = {hist0, hist1, hist2};
    int* rpA[3]   = {rp0, rp1, rp2};
    const int NdA[3] = {N1, N2, N3};
    for (int l = 0; l < 3; ++l) {
        int n = NdA[l];
        int nb = (n / 4 + 255) / 256;
        scan_bsum<<<nb, 256, 0, stream>>>(histA[l], n, bsums);
        scan_bscan<<<1, 256, 0, stream>>>(bsums, nb, rpA[l] + n);
        scan_apply<<<nb, 256, 0, stream>>>(histA[l], n, bsums, rpA[l]);
    }
    csr_fill_all<<<(Etot + 255) / 256, 256, 0, stream>>>(
        srcA[0], dstA[0], E[0], srcA[1], dstA[1], E[1], srcA[2], dstA[2], E[2],
        rp0, cur0, eid0, rp1, cur1, eid1, rp2, cur2, eid2);

    for (int pass = 0; pass < 2; ++pass) {
        const int* g = (pass == 0) ? nullptr : perm;
        float* OUT = (pass == 0) ? PF : NF;

        // ===== layer 0 (M=50000): gather + fused self/neigh gemm per chunk =====
        for (int lo = 0; lo < N1; lo += aggRows) {
            int ch = min(aggRows, N1 - lo);
            gather_mean<<<(ch + 3) / 4, 256, 0, stream>>>(
                x, flagp, g, rp0, eid0, lo, lo + ch, AGG);
            gemm256<<<(ch + 31) / 32, 256, 0, stream>>>(
                x, flagp, g, lo, AGG, WS[0], WN[0], BV[0], H1, ch, 0);
        }
        colstats_p1<<<NBLK, 256, 0, stream>>>(H1, N1, PS, PQ);
        colstats_p2<<<1, 256, 0, stream>>>(PS, PQ, sumS, sqS);
        bn_relu<<<((size_t)N1 * 32 + 255) / 256, 256, 0, stream>>>(H1, N1, sumS, sqS, G0, BE0);

        // ===== layer 1 (M=25000) =====
        gather_mean<<<(N2 + 3) / 4, 256, 0, stream>>>(
            H1, nullptr, nullptr, rp1, eid1, 0, N2, AGG);
        gemm256<<<(N2 + 31) / 32, 256, 0, stream>>>(
            H1, nullptr, nullptr, 0, AGG, WS[1], WN[1], BV[1], H2, N2, 0);
        colstats_p1<<<NBLK, 256, 0, stream>>>(H2, N2, PS, PQ);
        colstats_p2<<<1, 256, 0, stream>>>(PS, PQ, sumS, sqS);
        bn_relu<<<((size_t)N2 * 32 + 255) / 256, 256, 0, stream>>>(H2, N2, sumS, sqS, G1, BE1);

        // ===== layer 2 (M=12500), no BN =====
        gather_mean<<<(N3 + 3) / 4, 256, 0, stream>>>(
            H2, nullptr, nullptr, rp2, eid2, 0, N3, AGG);
        gemm256<<<(N3 + 31) / 32, 256, 0, stream>>>(
            H2, nullptr, nullptr, 0, AGG, WS[2], WN[2], BV[2], OUT, N3, 0);
    }

    // ---- summary / discriminator loss ----
    colstats_p1<<<NBLK, 256, 0, stream>>>(PF, N3, PS, PQ);
    colstats_p2<<<1, 256, 0, stream>>>(PS, PQ, sumS, sqS);
    make_ws<<<1, 128, 0, stream>>>(sumS, DW, wsvec, N3);
    loss_partial<<<NBLK, 256, 0, stream>>>(PF, NF, wsvec, lossP, lossN, N3);
    write_loss<<<1, 256, 0, stream>>>(lossP, lossN, d_out, N3, flagp);

    // ---- predictor MLP: pos pairs then neg pairs ----
    for (int c = 0; c < 2; ++c) {
        const int* si = (c == 0) ? pos_src : neg_src;
        const int* di = (c == 0) ? pos_dst : neg_dst;
        pair_mult<<<(EP + 1) / 2, 256, 0, stream>>>(PF, si, di, Z, EP);
        gemm128<<<(EP + 31) / 32, 256, 0, stream>>>(Z,  PW1, PB1, ZA, EP, 1);
        gemm128<<<(EP + 31) / 32, 256, 0, stream>>>(ZA, PW2, PB2, ZB, EP, 1);
        final_mv<<<(EP + 3) / 4, 256, 0, stream>>>(ZB, PW3, PB3, d_out, EP, c * EP, flagp);
    }
}

// Round 10
// 903.641 us; speedup vs baseline: 3.4199x; 1.1321x over previous
//
#include <hip/hip_runtime.h>
#include <hip/hip_bf16.h>

#define DD 128
#define BN_EPS 1e-5f
#define NBLK 160   // blocks for stats/loss partial kernels

typedef __hip_bfloat16 bf16;
typedef __attribute__((ext_vector_type(8))) short short8;
typedef __attribute__((ext_vector_type(4))) float f32x4;

__device__ __forceinline__ float b2f(unsigned short u) {
    union { float f; unsigned int i; } x; x.i = ((unsigned int)u) << 16; return x.f;
}
__device__ __forceinline__ unsigned short f2bs(float v) {
    bf16 h = __float2bfloat16(v);
    return *(unsigned short*)&h;
}

// ---- dtype detect: flag=1 if d_in[0] is packed bf16, 0 if f32 ----
__global__ void detect_dtype(const unsigned int* __restrict__ x, int* __restrict__ flag) {
    __shared__ int s[256];
    int t = threadIdx.x;
    unsigned int u = x[t];
    unsigned int e = (u >> 7) & 0xFFu;
    s[t] = ((e >= 90u && e <= 140u) || ((u & 0xFFFFu) == 0u)) ? 1 : 0;
    __syncthreads();
    for (int off = 128; off > 0; off >>= 1) { if (t < off) s[t] += s[t + off]; __syncthreads(); }
    if (t == 0) *flag = (s[0] >= 128) ? 1 : 0;
}

// ---- fused weight conversion ----
struct CvtTable {
    const void* src[20];
    int off[20];
    int n[20];
    int total;
};
__global__ __launch_bounds__(256) void cvt_all(CvtTable tab, float* __restrict__ wsf,
                                               const int* __restrict__ flagp) {
    int i = blockIdx.x * 256 + threadIdx.x;
    if (i >= tab.total) return;
    int k = 0;
    while (i >= tab.n[k]) { i -= tab.n[k]; ++k; }
    float v;
    if (*flagp) v = b2f(((const unsigned short*)tab.src[k])[i]);
    else        v = ((const float*)tab.src[k])[i];
    wsf[tab.off[k] + i] = v;
}

// ---- build MFMA B-fragment table from f32 W1 (+optional W2): KS = K/32 ----
// frag[(ct*KS + ks)*64 + lane] = 8 bf16: B[k = ks*32 + (lane>>4)*8 + j][n = ct*16 + (lane&15)]
__global__ __launch_bounds__(256) void make_wfrag(
    const float* __restrict__ W1, const float* __restrict__ W2, int KS,
    unsigned short* __restrict__ frag) {
    int t = blockIdx.x * 256 + threadIdx.x;
    int total = 8 * KS * 64;
    if (t >= total) return;
    int lane = t & 63;
    int ks = (t >> 6) % KS;
    int ct = t / (KS * 64);
    int n = ct * 16 + (lane & 15);
    unsigned short v[8];
#pragma unroll
    for (int j = 0; j < 8; ++j) {
        int k = ks * 32 + ((lane >> 4) & 3) * 8 + j;
        float w = (k < 128) ? W1[k * DD + n] : W2[(k - 128) * DD + n];
        v[j] = f2bs(w);
    }
    *(uint4*)&frag[(size_t)t * 8] = *(uint4*)v;
}

// ---- CSR build: fused histogram over all 3 layers ----
__global__ __launch_bounds__(256) void hist_all(
    const int* __restrict__ d0, int e0, const int* __restrict__ d1, int e1,
    const int* __restrict__ d2, int e2,
    int* __restrict__ h0, int* __restrict__ h1, int* __restrict__ h2) {
    int e = blockIdx.x * 256 + threadIdx.x;
    if (e < e0) atomicAdd(&h0[d0[e]], 1);
    else if (e < e0 + e1) atomicAdd(&h1[d1[e - e0]], 1);
    else if (e < e0 + e1 + e2) atomicAdd(&h2[d2[e - e0 - e1]], 1);
}

// ---- hierarchical exclusive scan (n % 4 == 0) ----
__global__ __launch_bounds__(256) void scan_bsum(const int* __restrict__ cnt, int n,
                                                 int* __restrict__ bsums) {
    __shared__ int sm[256];
    int t = threadIdx.x, b = blockIdx.x;
    int i4 = b * 256 + t;
    int local = 0;
    if (i4 * 4 < n) { int4 v = ((const int4*)cnt)[i4]; local = v.x + v.y + v.z + v.w; }
    sm[t] = local;
    __syncthreads();
    for (int off = 128; off > 0; off >>= 1) { if (t < off) sm[t] += sm[t + off]; __syncthreads(); }
    if (t == 0) bsums[b] = sm[0];
}
__global__ void scan_bscan(int* __restrict__ bsums, int nb, int* __restrict__ rowptr_n) {
    __shared__ int wsum[4];
    int t = threadIdx.x, lane = t & 63, w = t >> 6;
    int v = (t < nb) ? bsums[t] : 0;
    int inc = v;
    for (int off = 1; off < 64; off <<= 1) {
        int u = __shfl_up(inc, off, 64);
        if (lane >= off) inc += u;
    }
    if (lane == 63) wsum[w] = inc;
    __syncthreads();
    int wo = 0;
    for (int i = 0; i < w; ++i) wo += wsum[i];
    if (t < nb) bsums[t] = wo + inc - v;
    if (t == 255) *rowptr_n = wo + inc;
}
__global__ __launch_bounds__(256) void scan_apply(const int* __restrict__ cnt, int n,
                                                  const int* __restrict__ bsums,
                                                  int* __restrict__ rowptr) {
    __shared__ int wsum[4];
    int t = threadIdx.x, b = blockIdx.x, lane = t & 63, w = t >> 6;
    int i4 = b * 256 + t;
    int4 v = {0, 0, 0, 0};
    bool valid = (i4 * 4 < n);
    if (valid) v = ((const int4*)cnt)[i4];
    int local = v.x + v.y + v.z + v.w;
    int inc = local;
    for (int off = 1; off < 64; off <<= 1) {
        int u = __shfl_up(inc, off, 64);
        if (lane >= off) inc += u;
    }
    if (lane == 63) wsum[w] = inc;
    __syncthreads();
    int wo = 0;
    for (int i = 0; i < w; ++i) wo += wsum[i];
    if (valid) {
        int acc = bsums[b] + wo + inc - local;
        int base = i4 * 4;
        rowptr[base + 0] = acc; acc += v.x;
        rowptr[base + 1] = acc; acc += v.y;
        rowptr[base + 2] = acc; acc += v.z;
        rowptr[base + 3] = acc;
    }
}

// ---- CSR fill: fused over all 3 layers ----
__global__ __launch_bounds__(256) void csr_fill_all(
    const int* __restrict__ s0, const int* __restrict__ d0, int e0,
    const int* __restrict__ s1, const int* __restrict__ d1, int e1,
    const int* __restrict__ s2, const int* __restrict__ d2, int e2,
    const int* __restrict__ rp0, int* __restrict__ cu0, int* __restrict__ ei0,
    const int* __restrict__ rp1, int* __restrict__ cu1, int* __restrict__ ei1,
    const int* __restrict__ rp2, int* __restrict__ cu2, int* __restrict__ ei2) {
    int e = blockIdx.x * 256 + threadIdx.x;
    if (e < e0) {
        int d = d0[e];
        ei0[rp0[d] + atomicAdd(&cu0[d], 1)] = s0[e];
    } else if (e < e0 + e1) {
        int i = e - e0, d = d1[i];
        ei1[rp1[d] + atomicAdd(&cu1[d], 1)] = s1[i];
    } else if (e < e0 + e1 + e2) {
        int i = e - e0 - e1, d = d2[i];
        ei2[rp2[d] + atomicAdd(&cu2[d], 1)] = s2[i];
    }
}

// ---- CSR gather: one wave per dst row, lane covers 2 features, 4-deep unroll ----
__global__ __launch_bounds__(256) void gather_mean(
    const void* __restrict__ hv, const int* __restrict__ flagp, const int* __restrict__ perm,
    const int* __restrict__ rowptr, const int* __restrict__ eid,
    int lo, int hi, float* __restrict__ out)
{
    int d = lo + blockIdx.x * 4 + (threadIdx.x >> 6);
    int lane = threadIdx.x & 63;
    if (d >= hi) return;
    int i0 = rowptr[d], i1 = rowptr[d + 1];
    int abf = flagp ? *flagp : 0;
    float a0x = 0, a0y = 0, a1x = 0, a1y = 0, a2x = 0, a2y = 0, a3x = 0, a3y = 0;
    int i = i0;
    if (abf) {
        const unsigned short* h = (const unsigned short*)hv;
        for (; i + 4 <= i1; i += 4) {
            int s0 = eid[i], s1 = eid[i + 1], s2 = eid[i + 2], s3 = eid[i + 3];
            if (perm) { s0 = perm[s0]; s1 = perm[s1]; s2 = perm[s2]; s3 = perm[s3]; }
            ushort2 v0 = *(const ushort2*)&h[(size_t)s0 * DD + lane * 2];
            ushort2 v1 = *(const ushort2*)&h[(size_t)s1 * DD + lane * 2];
            ushort2 v2 = *(const ushort2*)&h[(size_t)s2 * DD + lane * 2];
            ushort2 v3 = *(const ushort2*)&h[(size_t)s3 * DD + lane * 2];
            a0x += b2f(v0.x); a0y += b2f(v0.y);
            a1x += b2f(v1.x); a1y += b2f(v1.y);
            a2x += b2f(v2.x); a2y += b2f(v2.y);
            a3x += b2f(v3.x); a3y += b2f(v3.y);
        }
        for (; i < i1; ++i) {
            int s = eid[i];
            if (perm) s = perm[s];
            ushort2 v = *(const ushort2*)&h[(size_t)s * DD + lane * 2];
            a0x += b2f(v.x); a0y += b2f(v.y);
        }
    } else {
        const float* h = (const float*)hv;
        for (; i + 4 <= i1; i += 4) {
            int s0 = eid[i], s1 = eid[i + 1], s2 = eid[i + 2], s3 = eid[i + 3];
            if (perm) { s0 = perm[s0]; s1 = perm[s1]; s2 = perm[s2]; s3 = perm[s3]; }
            float2 v0 = *(const float2*)&h[(size_t)s0 * DD + lane * 2];
            float2 v1 = *(const float2*)&h[(size_t)s1 * DD + lane * 2];
            float2 v2 = *(const float2*)&h[(size_t)s2 * DD + lane * 2];
            float2 v3 = *(const float2*)&h[(size_t)s3 * DD + lane * 2];
            a0x += v0.x; a0y += v0.y;
            a1x += v1.x; a1y += v1.y;
            a2x += v2.x; a2y += v2.y;
            a3x += v3.x; a3y += v3.y;
        }
        for (; i < i1; ++i) {
            int s = eid[i];
            if (perm) s = perm[s];
            float2 v = *(const float2*)&h[(size_t)s * DD + lane * 2];
            a0x += v.x; a0y += v.y;
        }
    }
    float rd = 1.0f / fmaxf((float)(i1 - i0), 1.0f);
    float2 o;
    o.x = (a0x + a1x + a2x + a3x) * rd;
    o.y = (a0y + a1y + a2y + a3y) * rd;
    *(float2*)&out[(size_t)(d - lo) * DD + lane * 2] = o;
}

// ---- MFMA GEMM: out[lo+r] = concat(A1[g(lo+r)], A2[r]) @ W + bias ----
// K = 256 if A2 != null else 128. W pre-swizzled fragment table (make_wfrag).
// Block: 64 rows x 128 cols, 4 waves; wave w does rows w*16..w*16+16, 8 col-tiles.
#define ALD 264   // LDS row stride in bf16 (256 + 8 pad)
__global__ __launch_bounds__(256) void mfma_gemm(
    const void* __restrict__ A1v, const int* __restrict__ flagp,
    const int* __restrict__ gather, int lo,
    const float* __restrict__ A2,
    const uint4* __restrict__ wfrag, const float* __restrict__ bias,
    float* __restrict__ out, int Mc, int relu)
{
    __shared__ unsigned short As[64 * ALD];
    const int tid = threadIdx.x;
    const int rb = blockIdx.x * 64;
    const int abf = flagp ? *flagp : 0;
    const int KS = A2 ? 8 : 4;

    { // stage A: thread covers row = tid>>2, 32 cols at (tid&3)*32
        int r = tid >> 2, cs = (tid & 3) * 32;
        int gr = rb + r;
        unsigned short* dst = &As[r * ALD + cs];
        if (gr < Mc) {
            int ar = gather ? gather[lo + gr] : (lo + gr);
            if (abf) {
                const uint4* s = (const uint4*)((const unsigned short*)A1v + (size_t)ar * DD + cs);
                uint4* dv = (uint4*)dst;
#pragma unroll
                for (int i = 0; i < 4; ++i) dv[i] = s[i];
            } else {
                const float* s = (const float*)A1v + (size_t)ar * DD + cs;
#pragma unroll
                for (int i = 0; i < 32; ++i) dst[i] = f2bs(s[i]);
            }
            if (A2) {
                const float* s2 = A2 + (size_t)gr * DD + cs;
                unsigned short* d2 = dst + 128;
#pragma unroll
                for (int i = 0; i < 32; ++i) d2[i] = f2bs(s2[i]);
            }
        } else {
            uint4 z = {0, 0, 0, 0};
            uint4* dv = (uint4*)dst;
#pragma unroll
            for (int i = 0; i < 4; ++i) dv[i] = z;
            if (A2) {
                uint4* d2 = (uint4*)(dst + 128);
#pragma unroll
                for (int i = 0; i < 4; ++i) d2[i] = z;
            }
        }
    }
    __syncthreads();

    const int w = tid >> 6, lane = tid & 63;
    const int m0 = w * 16;
    f32x4 acc[8] = {};

    for (int ks = 0; ks < KS; ++ks) {
        short8 a = *(const short8*)&As[(m0 + (lane & 15)) * ALD + ks * 32 + ((lane >> 4) & 3) * 8];
#pragma unroll
        for (int ct = 0; ct < 8; ++ct) {
            uint4 braw = wfrag[(ct * KS + ks) * 64 + lane];
            short8 b = *(short8*)&braw;
            acc[ct] = __builtin_amdgcn_mfma_f32_16x16x32_bf16(a, b, acc[ct], 0, 0, 0);
        }
    }

#pragma unroll
    for (int ct = 0; ct < 8; ++ct) {
        int col = ct * 16 + (lane & 15);
        float bv = bias[col];
#pragma unroll
        for (int r = 0; r < 4; ++r) {
            int grow = rb + m0 + ((lane >> 4) & 3) * 4 + r;
            if (grow >= Mc) continue;
            float v = acc[ct][r] + bv;
            if (relu) v = fmaxf(v, 0.0f);
            out[(size_t)(lo + grow) * DD + col] = v;
        }
    }
}

// ---- column stats stage 1 ----
__global__ __launch_bounds__(256) void colstats_p1(
    const float* __restrict__ t, int M,
    float* __restrict__ PS, float* __restrict__ PQ)
{
    __shared__ float sm[256], sq2[256];
    int tid = threadIdx.x;
    int c = tid & 127, h = tid >> 7;
    int rpb = (M + NBLK - 1) / NBLK;
    int r0 = blockIdx.x * rpb;
    int r1 = min(r0 + rpb, M);
    float s = 0.0f, ss = 0.0f;
    for (int r = r0 + h; r < r1; r += 2) {
        float v = t[(size_t)r * DD + c];
        s += v; ss += v * v;
    }
    sm[tid] = s; sq2[tid] = ss;
    __syncthreads();
    if (tid < 128) {
        PS[blockIdx.x * 128 + tid] = sm[tid] + sm[tid + 128];
        PQ[blockIdx.x * 128 + tid] = sq2[tid] + sq2[tid + 128];
    }
}

// ---- column stats stage 2 ----
__global__ void colstats_p2(const float* __restrict__ PS, const float* __restrict__ PQ,
                            float* __restrict__ sum, float* __restrict__ sumsq) {
    int t = threadIdx.x;  // 256
    float a = 0.0f;
    if (t < 128) {
        for (int b = 0; b < NBLK; ++b) a += PS[b * 128 + t];
        sum[t] = a;
    } else {
        int c = t - 128;
        for (int b = 0; b < NBLK; ++b) a += PQ[b * 128 + c];
        sumsq[c] = a;
    }
}

// ---- BN + ReLU, in place, float4 ----
__global__ __launch_bounds__(256) void bn_relu(
    float* __restrict__ h, int M, const float* __restrict__ sum, const float* __restrict__ sumsq,
    const float* __restrict__ gamma, const float* __restrict__ beta) {
    size_t i4 = (size_t)blockIdx.x * blockDim.x + threadIdx.x;
    size_t n4 = (size_t)M * 32;
    if (i4 >= n4) return;
    int c = (i4 & 31) * 4;
    float4 v = ((float4*)h)[i4];
    float inv[4], m[4], g[4], be[4];
#pragma unroll
    for (int j = 0; j < 4; ++j) {
        m[j] = sum[c + j] / (float)M;
        float var = fmaxf(sumsq[c + j] / (float)M - m[j] * m[j], 0.0f);
        inv[j] = rsqrtf(var + BN_EPS);
        g[j] = gamma[c + j]; be[j] = beta[c + j];
    }
    v.x = fmaxf(g[0] * (v.x - m[0]) * inv[0] + be[0], 0.0f);
    v.y = fmaxf(g[1] * (v.y - m[1]) * inv[1] + be[1], 0.0f);
    v.z = fmaxf(g[2] * (v.z - m[2]) * inv[2] + be[2], 0.0f);
    v.w = fmaxf(g[3] * (v.w - m[3]) * inv[3] + be[3], 0.0f);
    ((float4*)h)[i4] = v;
}

// ---- summary -> wsvec ----
__global__ void make_ws(const float* __restrict__ colsum, const float* __restrict__ discW,
                        float* __restrict__ wsv, int M) {
    __shared__ float s[128];
    int t = threadIdx.x;  // 128
    s[t] = 1.0f / (1.0f + expf(-(colsum[t] / (float)M)));
    __syncthreads();
    float acc = 0.0f;
    for (int j = 0; j < 128; ++j) acc += discW[t * 128 + j] * s[j];
    wsv[t] = acc;
}

// ---- loss stage 1 ----
__global__ __launch_bounds__(256) void loss_partial(
    const float* __restrict__ P, const float* __restrict__ Ng,
    const float* __restrict__ wsv, float* __restrict__ lossP, float* __restrict__ lossN, int M)
{
    __shared__ float sP[4], sN[4];
    int lane = threadIdx.x & 63;
    int wave = threadIdx.x >> 6;
    int gw = blockIdx.x * 4 + wave;
    int nw = gridDim.x * 4;
    float w0 = wsv[lane], w1 = wsv[lane + 64];
    float accP = 0.0f, accN = 0.0f;
    for (int row = gw; row < 2 * M; row += nw) {
        const float* base = (row < M) ? &P[(size_t)row * DD] : &Ng[(size_t)(row - M) * DD];
        float a = base[lane] * w0 + base[lane + 64] * w1;
#pragma unroll
        for (int off = 32; off > 0; off >>= 1) a += __shfl_down(a, off, 64);
        if (lane == 0) {
            float x = (row < M) ? -a : a;
            float sp = fmaxf(x, 0.0f) + log1pf(expf(-fabsf(x)));
            if (row < M) accP += sp; else accN += sp;
        }
    }
    if (lane == 0) { sP[wave] = accP; sN[wave] = accN; }
    __syncthreads();
    if (threadIdx.x == 0) {
        lossP[blockIdx.x] = sP[0] + sP[1] + sP[2] + sP[3];
        lossN[blockIdx.x] = sN[0] + sN[1] + sN[2] + sN[3];
    }
}

// ---- loss stage 2 ----
__global__ void write_loss(const float* __restrict__ lossP, const float* __restrict__ lossN,
                           void* __restrict__ outv, int M, const int* __restrict__ flagp) {
    __shared__ float s[256];
    int t = threadIdx.x;  // 256
    s[t] = (t < NBLK) ? (lossP[t] + lossN[t]) : 0.0f;
    __syncthreads();
    for (int off = 128; off > 0; off >>= 1) { if (t < off) s[t] += s[t + off]; __syncthreads(); }
    if (t == 0) {
        float v = s[0] / (float)M;
        if (*flagp) ((bf16*)outv)[20000] = __float2bfloat16(v);
        else        ((float*)outv)[20000] = v;
    }
}

// ---- predictor input ----
__global__ __launch_bounds__(256) void pair_mult(
    const float* __restrict__ P, const int* __restrict__ s_idx, const int* __restrict__ d_idx,
    float* __restrict__ Z, int nPair) {
    int i = blockIdx.x * 2 + (threadIdx.x >> 7);
    int f = threadIdx.x & 127;
    if (i >= nPair) return;
    Z[(size_t)i * DD + f] = P[(size_t)s_idx[i] * DD + f] * P[(size_t)d_idx[i] * DD + f];
}

// ---- final 128 -> 1 matvec ----
__global__ __launch_bounds__(256) void final_mv(
    const float* __restrict__ ZB, const float* __restrict__ pW3, const float* __restrict__ pb3,
    void* __restrict__ outv, int nRows, int outOff, const int* __restrict__ flagp) {
    int row = blockIdx.x * 4 + (threadIdx.x >> 6);
    int lane = threadIdx.x & 63;
    if (row >= nRows) return;
    float a = ZB[(size_t)row * DD + lane] * pW3[lane]
            + ZB[(size_t)row * DD + lane + 64] * pW3[lane + 64];
#pragma unroll
    for (int off = 32; off > 0; off >>= 1) a += __shfl_down(a, off, 64);
    if (lane == 0) {
        float v = a + pb3[0];
        if (*flagp) ((bf16*)outv)[outOff + row] = __float2bfloat16(v);
        else        ((float*)outv)[outOff + row] = v;
    }
}

extern "C" void kernel_launch(void* const* d_in, const int* in_sizes, int n_in,
                              void* d_out, int out_size, void* d_ws, size_t ws_size,
                              hipStream_t stream)
{
    const void* x      = d_in[0];
    const int* srcA[3] = {(const int*)d_in[1], (const int*)d_in[3], (const int*)d_in[5]};
    const int* dstA[3] = {(const int*)d_in[2], (const int*)d_in[4], (const int*)d_in[6]};
    const int* perm    = (const int*)d_in[7];
    const int* pos_src = (const int*)d_in[8];
    const int* pos_dst = (const int*)d_in[9];
    const int* neg_src = (const int*)d_in[10];
    const int* neg_dst = (const int*)d_in[11];

    const int N1 = 50000, N2 = 25000, N3 = 12500;
    const int E[3] = {750000, 250000, 125000};
    const int EP = 10000;

    // ---- ws layout (4-byte units) ----
    float* wsf = (float*)d_ws;
    int*   wsi = (int*)d_ws;
    int*   flagp = wsi;
    float* PS    = wsf + 256;
    float* PQ    = wsf + 20736;
    float* lossP = wsf + 41216;
    float* lossN = wsf + 41376;
    float* sumS  = wsf + 41600;
    float* sqS   = wsf + 41728;
    float* wsvec = wsf + 41856;
    int*   bsums = wsi + 41984;                   // 256 scan scratch
    // hist region 43008..218060 — dead after csr_fill; REUSED for wfrag tables
    int* hist0 = wsi + 43008;
    int* hist1 = wsi + 93008;
    int* hist2 = wsi + 118008;
    int* cur0  = wsi + 130560;
    int* cur1  = wsi + 180560;
    int* cur2  = wsi + 205560;
    unsigned short* wfragL[3] = {(unsigned short*)(wsi + 43008),
                                 (unsigned short*)(wsi + 59392),
                                 (unsigned short*)(wsi + 75776)};   // 16384 fl each (K=256)
    unsigned short* wfragP[2] = {(unsigned short*)(wsi + 92160),
                                 (unsigned short*)(wsi + 100352)};  // 8192 fl each (K=128)
    int* rp0   = wsi + 218112;
    int* rp1   = wsi + 268160;
    int* rp2   = wsi + 293248;
    int* eid0  = wsi + 305792;
    int* eid1  = wsi + 1055792;
    int* eid2  = wsi + 1305792;
    const size_t WfB = 1431040;
    float* WS[3] = {wsf + WfB +      0, wsf + WfB +  32896, wsf + WfB +  65792};
    float* WN[3] = {wsf + WfB +  16384, wsf + WfB +  49280, wsf + WfB +  82176};
    float* BV[3] = {wsf + WfB +  32768, wsf + WfB +  65664, wsf + WfB +  98560};
    float* G0  = wsf + WfB +  98688; float* BE0 = wsf + WfB +  98816;
    float* G1  = wsf + WfB +  98944; float* BE1 = wsf + WfB +  99072;
    float* DW  = wsf + WfB +  99200;
    float* PW1 = wsf + WfB + 115584; float* PB1 = wsf + WfB + 131968;
    float* PW2 = wsf + WfB + 132096; float* PB2 = wsf + WfB + 148480;
    float* PW3 = wsf + WfB + 148608; float* PB3 = wsf + WfB + 148736;
    float* PF  = wsf + 1580032;                   // 1,600,000
    float* NF  = wsf + 3180032;                   // 1,600,000
    float* H2  = wsf + 4780032;                   // 3,200,000
    float* H1  = wsf + 7980032;                   // 6,400,000
    float* AGG = wsf + 14380032;                  // up to 6,400,000
    float* Z  = H1;
    float* ZA = H1 + 1280000;
    float* ZB = H1 + 2560000;

    int aggRows = (ws_size >= (size_t)(14380032 + 6400000) * 4) ? 50000 : 25000;

    // ---- dtype detect + fused weight conversion ----
    detect_dtype<<<1, 256, 0, stream>>>((const unsigned int*)x, flagp);
    CvtTable tab;
    const int widx[20] = {12,13,14, 15,16,17, 18,19,20, 21,22,23,24, 25, 26,27, 28,29, 30,31};
    float* wdst[20] = {WS[0],WN[0],BV[0], WS[1],WN[1],BV[1], WS[2],WN[2],BV[2],
                       G0,BE0,G1,BE1, DW, PW1,PB1, PW2,PB2, PW3,PB3};
    const int wn[20] = {16384,16384,128, 16384,16384,128, 16384,16384,128,
                        128,128,128,128, 16384, 16384,128, 16384,128, 128,1};
    int tot = 0;
    for (int k = 0; k < 20; ++k) {
        tab.src[k] = d_in[widx[k]];
        tab.off[k] = (int)(wdst[k] - wsf);
        tab.n[k] = wn[k];
        tot += wn[k];
    }
    tab.total = tot;
    cvt_all<<<(tot + 255) / 256, 256, 0, stream>>>(tab, wsf, flagp);

    // ---- CSR build (uses hist region; must finish before wfrag overwrites it) ----
    hipMemsetAsync(hist0, 0, (size_t)(218060 - 43008) * 4, stream);
    int Etot = E[0] + E[1] + E[2];
    hist_all<<<(Etot + 255) / 256, 256, 0, stream>>>(
        dstA[0], E[0], dstA[1], E[1], dstA[2], E[2], hist0, hist1, hist2);
    int* histA[3] = {hist0, hist1, hist2};
    int* rpA[3]   = {rp0, rp1, rp2};
    const int NdA[3] = {N1, N2, N3};
    for (int l = 0; l < 3; ++l) {
        int n = NdA[l];
        int nb = (n / 4 + 255) / 256;
        scan_bsum<<<nb, 256, 0, stream>>>(histA[l], n, bsums);
        scan_bscan<<<1, 256, 0, stream>>>(bsums, nb, rpA[l] + n);
        scan_apply<<<nb, 256, 0, stream>>>(histA[l], n, bsums, rpA[l]);
    }
    csr_fill_all<<<(Etot + 255) / 256, 256, 0, stream>>>(
        srcA[0], dstA[0], E[0], srcA[1], dstA[1], E[1], srcA[2], dstA[2], E[2],
        rp0, cur0, eid0, rp1, cur1, eid1, rp2, cur2, eid2);

    // ---- build MFMA W-fragment tables (hist region now dead) ----
    for (int l = 0; l < 3; ++l)
        make_wfrag<<<(8 * 8 * 64 + 255) / 256, 256, 0, stream>>>(WS[l], WN[l], 8, wfragL[l]);
    make_wfrag<<<(8 * 4 * 64 + 255) / 256, 256, 0, stream>>>(PW1, nullptr, 4, wfragP[0]);
    make_wfrag<<<(8 * 4 * 64 + 255) / 256, 256, 0, stream>>>(PW2, nullptr, 4, wfragP[1]);

    for (int pass = 0; pass < 2; ++pass) {
        const int* g = (pass == 0) ? nullptr : perm;
        float* OUT = (pass == 0) ? PF : NF;

        // ===== layer 0 (M=50000) =====
        for (int lo = 0; lo < N1; lo += aggRows) {
            int ch = min(aggRows, N1 - lo);
            gather_mean<<<(ch + 3) / 4, 256, 0, stream>>>(
                x, flagp, g, rp0, eid0, lo, lo + ch, AGG);
            mfma_gemm<<<(ch + 63) / 64, 256, 0, stream>>>(
                x, flagp, g, lo, AGG, (const uint4*)wfragL[0], BV[0], H1, ch, 0);
        }
        colstats_p1<<<NBLK, 256, 0, stream>>>(H1, N1, PS, PQ);
        colstats_p2<<<1, 256, 0, stream>>>(PS, PQ, sumS, sqS);
        bn_relu<<<((size_t)N1 * 32 + 255) / 256, 256, 0, stream>>>(H1, N1, sumS, sqS, G0, BE0);

        // ===== layer 1 (M=25000) =====
        gather_mean<<<(N2 + 3) / 4, 256, 0, stream>>>(
            H1, nullptr, nullptr, rp1, eid1, 0, N2, AGG);
        mfma_gemm<<<(N2 + 63) / 64, 256, 0, stream>>>(
            H1, nullptr, nullptr, 0, AGG, (const uint4*)wfragL[1], BV[1], H2, N2, 0);
        colstats_p1<<<NBLK, 256, 0, stream>>>(H2, N2, PS, PQ);
        colstats_p2<<<1, 256, 0, stream>>>(PS, PQ, sumS, sqS);
        bn_relu<<<((size_t)N2 * 32 + 255) / 256, 256, 0, stream>>>(H2, N2, sumS, sqS, G1, BE1);

        // ===== layer 2 (M=12500), no BN =====
        gather_mean<<<(N3 + 3) / 4, 256, 0, stream>>>(
            H2, nullptr, nullptr, rp2, eid2, 0, N3, AGG);
        mfma_gemm<<<(N3 + 63) / 64, 256, 0, stream>>>(
            H2, nullptr, nullptr, 0, AGG, (const uint4*)wfragL[2], BV[2], OUT, N3, 0);
    }

    // ---- summary / discriminator loss ----
    colstats_p1<<<NBLK, 256, 0, stream>>>(PF, N3, PS, PQ);
    colstats_p2<<<1, 256, 0, stream>>>(PS, PQ, sumS, sqS);
    make_ws<<<1, 128, 0, stream>>>(sumS, DW, wsvec, N3);
    loss_partial<<<NBLK, 256, 0, stream>>>(PF, NF, wsvec, lossP, lossN, N3);
    write_loss<<<1, 256, 0, stream>>>(lossP, lossN, d_out, N3, flagp);

    // ---- predictor MLP: pos pairs then neg pairs ----
    for (int c = 0; c < 2; ++c) {
        const int* si = (c == 0) ? pos_src : neg_src;
        const int* di = (c == 0) ? pos_dst : neg_dst;
        pair_mult<<<(EP + 1) / 2, 256, 0, stream>>>(PF, si, di, Z, EP);
        mfma_gemm<<<(EP + 63) / 64, 256, 0, stream>>>(
            Z, nullptr, nullptr, 0, nullptr, (const uint4*)wfragP[0], PB1, ZA, EP, 1);
        mfma_gemm<<<(EP + 63) / 64, 256, 0, stream>>>(
            ZA, nullptr, nullptr, 0, nullptr, (const uint4*)wfragP[1], PB2, ZB, EP, 1);
        final_mv<<<(EP + 3) / 4, 256, 0, stream>>>(ZB, PW3, PB3, d_out, EP, c * EP, flagp);
    }
}

// Round 11
// 843.579 us; speedup vs baseline: 3.6634x; 1.0712x over previous
//
#include <hip/hip_runtime.h>
#include <hip/hip_bf16.h>

#define DD 128
#define BN_EPS 1e-5f
#define NBLK 160   // blocks for stats/loss partial kernels

typedef __hip_bfloat16 bf16;
typedef __attribute__((ext_vector_type(8))) short short8;
typedef __attribute__((ext_vector_type(4))) float f32x4;

__device__ __forceinline__ float b2f(unsigned short u) {
    union { float f; unsigned int i; } x; x.i = ((unsigned int)u) << 16; return x.f;
}
__device__ __forceinline__ unsigned short f2bs(float v) {
    bf16 h = __float2bfloat16(v);
    return *(unsigned short*)&h;
}

// ---- dtype detect: flag=1 if d_in[0] is packed bf16, 0 if f32 ----
__global__ void detect_dtype(const unsigned int* __restrict__ x, int* __restrict__ flag) {
    __shared__ int s[256];
    int t = threadIdx.x;
    unsigned int u = x[t];
    unsigned int e = (u >> 7) & 0xFFu;
    s[t] = ((e >= 90u && e <= 140u) || ((u & 0xFFFFu) == 0u)) ? 1 : 0;
    __syncthreads();
    for (int off = 128; off > 0; off >>= 1) { if (t < off) s[t] += s[t + off]; __syncthreads(); }
    if (t == 0) *flag = (s[0] >= 128) ? 1 : 0;
}

// ---- fused weight conversion ----
struct CvtTable {
    const void* src[20];
    int off[20];
    int n[20];
    int total;
};
__global__ __launch_bounds__(256) void cvt_all(CvtTable tab, float* __restrict__ wsf,
                                               const int* __restrict__ flagp) {
    int i = blockIdx.x * 256 + threadIdx.x;
    if (i >= tab.total) return;
    int k = 0;
    while (i >= tab.n[k]) { i -= tab.n[k]; ++k; }
    float v;
    if (*flagp) v = b2f(((const unsigned short*)tab.src[k])[i]);
    else        v = ((const float*)tab.src[k])[i];
    wsf[tab.off[k] + i] = v;
}

// ---- fused MFMA B-fragment builder (5 tables) ----
struct WfAll {
    const float* W1[5];
    const float* W2[5];
    unsigned short* dst[5];
    int KS[5];
    int start[5];
    int total;
};
__global__ __launch_bounds__(256) void wfrag_all(WfAll w) {
    int t = blockIdx.x * 256 + threadIdx.x;
    if (t >= w.total) return;
    int k = 0;
    while (k < 4 && t >= w.start[k + 1]) ++k;
    int lt = t - w.start[k];
    int KS = w.KS[k];
    int lane = lt & 63;
    int ks = (lt >> 6) % KS;
    int ct = lt / (KS * 64);
    int n = ct * 16 + (lane & 15);
    unsigned short v[8];
#pragma unroll
    for (int j = 0; j < 8; ++j) {
        int kk = ks * 32 + ((lane >> 4) & 3) * 8 + j;
        float wv = (kk < 128) ? w.W1[k][kk * DD + n] : w.W2[k][(kk - 128) * DD + n];
        v[j] = f2bs(wv);
    }
    *(uint4*)&w.dst[k][(size_t)lt * 8] = *(uint4*)v;
}

// ---- CSR: windowed histogram over concatenated dst space (write-locality) ----
__global__ __launch_bounds__(256) void hist_win(
    const int* __restrict__ d0, int e0, const int* __restrict__ d1, int e1,
    const int* __restrict__ d2, int e2, int* __restrict__ hist) {
    int stride = gridDim.x * 256;
    int t0 = blockIdx.x * 256 + threadIdx.x;
    for (int w = 0; w < 4; ++w) {
        int dlo = w * 12500, dhi = dlo + 12500;
        for (int e = t0; e < e0; e += stride) {
            int d = d0[e];
            if (d >= dlo && d < dhi) atomicAdd(&hist[d], 1);
        }
    }
    for (int e = t0; e < e1; e += stride) atomicAdd(&hist[50000 + d1[e]], 1);
    for (int e = t0; e < e2; e += stride) atomicAdd(&hist[75000 + d2[e]], 1);
}

// ---- hierarchical exclusive scan over concatenated 87500 counts ----
__global__ __launch_bounds__(256) void scan_bsum(const int* __restrict__ cnt, int n,
                                                 int* __restrict__ bsums) {
    __shared__ int sm[256];
    int t = threadIdx.x, b = blockIdx.x;
    int i4 = b * 256 + t;
    int local = 0;
    if (i4 * 4 < n) { int4 v = ((const int4*)cnt)[i4]; local = v.x + v.y + v.z + v.w; }
    sm[t] = local;
    __syncthreads();
    for (int off = 128; off > 0; off >>= 1) { if (t < off) sm[t] += sm[t + off]; __syncthreads(); }
    if (t == 0) bsums[b] = sm[0];
}
__global__ void scan_bscan(int* __restrict__ bsums, int nb, int* __restrict__ rowptr_n) {
    __shared__ int wsum[4];
    int t = threadIdx.x, lane = t & 63, w = t >> 6;
    int v = (t < nb) ? bsums[t] : 0;
    int inc = v;
    for (int off = 1; off < 64; off <<= 1) {
        int u = __shfl_up(inc, off, 64);
        if (lane >= off) inc += u;
    }
    if (lane == 63) wsum[w] = inc;
    __syncthreads();
    int wo = 0;
    for (int i = 0; i < w; ++i) wo += wsum[i];
    if (t < nb) bsums[t] = wo + inc - v;
    if (t == 255) *rowptr_n = wo + inc;
}
__global__ __launch_bounds__(256) void scan_apply(const int* __restrict__ cnt, int n,
                                                  const int* __restrict__ bsums,
                                                  int* __restrict__ rowptr) {
    __shared__ int wsum[4];
    int t = threadIdx.x, b = blockIdx.x, lane = t & 63, w = t >> 6;
    int i4 = b * 256 + t;
    int4 v = {0, 0, 0, 0};
    bool valid = (i4 * 4 < n);
    if (valid) v = ((const int4*)cnt)[i4];
    int local = v.x + v.y + v.z + v.w;
    int inc = local;
    for (int off = 1; off < 64; off <<= 1) {
        int u = __shfl_up(inc, off, 64);
        if (lane >= off) inc += u;
    }
    if (lane == 63) wsum[w] = inc;
    __syncthreads();
    int wo = 0;
    for (int i = 0; i < w; ++i) wo += wsum[i];
    if (valid) {
        int acc = bsums[b] + wo + inc - local;
        int base = i4 * 4;
        rowptr[base + 0] = acc; acc += v.x;
        rowptr[base + 1] = acc; acc += v.y;
        rowptr[base + 2] = acc; acc += v.z;
        rowptr[base + 3] = acc;
    }
}

// ---- CSR fill, windowed by dst range for write locality ----
__global__ __launch_bounds__(256) void csr_fill_win(
    const int* __restrict__ s0, const int* __restrict__ d0, int e0,
    const int* __restrict__ s1, const int* __restrict__ d1, int e1,
    const int* __restrict__ s2, const int* __restrict__ d2, int e2,
    const int* __restrict__ rpAll, int* __restrict__ cur, int* __restrict__ eid) {
    int stride = gridDim.x * 256;
    int t0 = blockIdx.x * 256 + threadIdx.x;
    for (int w = 0; w < 4; ++w) {
        int dlo = w * 12500, dhi = dlo + 12500;
        for (int e = t0; e < e0; e += stride) {
            int d = d0[e];
            if (d >= dlo && d < dhi)
                eid[rpAll[d] + atomicAdd(&cur[d], 1)] = s0[e];
        }
    }
    for (int e = t0; e < e1; e += stride) {
        int gd = 50000 + d1[e];
        eid[rpAll[gd] + atomicAdd(&cur[gd], 1)] = s1[e];
    }
    for (int e = t0; e < e2; e += stride) {
        int gd = 75000 + d2[e];
        eid[rpAll[gd] + atomicAdd(&cur[gd], 1)] = s2[e];
    }
}

// ---- CSR gather -> bf16 mean rows. abf: flagp ? *flagp : 1 (internal bufs bf16) ----
__global__ __launch_bounds__(256) void gather_mean(
    const void* __restrict__ hv, const int* __restrict__ flagp, const int* __restrict__ perm,
    const int* __restrict__ rowptr, const int* __restrict__ eid,
    int lo, int hi, unsigned short* __restrict__ out)
{
    int d = lo + blockIdx.x * 4 + (threadIdx.x >> 6);
    int lane = threadIdx.x & 63;
    if (d >= hi) return;
    int i0 = rowptr[d], i1 = rowptr[d + 1];
    int abf = flagp ? *flagp : 1;
    float a0x = 0, a0y = 0, a1x = 0, a1y = 0, a2x = 0, a2y = 0, a3x = 0, a3y = 0;
    int i = i0;
    if (abf) {
        const unsigned short* h = (const unsigned short*)hv;
        for (; i + 4 <= i1; i += 4) {
            int s0 = eid[i], s1 = eid[i + 1], s2 = eid[i + 2], s3 = eid[i + 3];
            if (perm) { s0 = perm[s0]; s1 = perm[s1]; s2 = perm[s2]; s3 = perm[s3]; }
            ushort2 v0 = *(const ushort2*)&h[(size_t)s0 * DD + lane * 2];
            ushort2 v1 = *(const ushort2*)&h[(size_t)s1 * DD + lane * 2];
            ushort2 v2 = *(const ushort2*)&h[(size_t)s2 * DD + lane * 2];
            ushort2 v3 = *(const ushort2*)&h[(size_t)s3 * DD + lane * 2];
            a0x += b2f(v0.x); a0y += b2f(v0.y);
            a1x += b2f(v1.x); a1y += b2f(v1.y);
            a2x += b2f(v2.x); a2y += b2f(v2.y);
            a3x += b2f(v3.x); a3y += b2f(v3.y);
        }
        for (; i < i1; ++i) {
            int s = eid[i];
            if (perm) s = perm[s];
            ushort2 v = *(const ushort2*)&h[(size_t)s * DD + lane * 2];
            a0x += b2f(v.x); a0y += b2f(v.y);
        }
    } else {
        const float* h = (const float*)hv;
        for (; i + 4 <= i1; i += 4) {
            int s0 = eid[i], s1 = eid[i + 1], s2 = eid[i + 2], s3 = eid[i + 3];
            if (perm) { s0 = perm[s0]; s1 = perm[s1]; s2 = perm[s2]; s3 = perm[s3]; }
            float2 v0 = *(const float2*)&h[(size_t)s0 * DD + lane * 2];
            float2 v1 = *(const float2*)&h[(size_t)s1 * DD + lane * 2];
            float2 v2 = *(const float2*)&h[(size_t)s2 * DD + lane * 2];
            float2 v3 = *(const float2*)&h[(size_t)s3 * DD + lane * 2];
            a0x += v0.x; a0y += v0.y;
            a1x += v1.x; a1y += v1.y;
            a2x += v2.x; a2y += v2.y;
            a3x += v3.x; a3y += v3.y;
        }
        for (; i < i1; ++i) {
            int s = eid[i];
            if (perm) s = perm[s];
            float2 v = *(const float2*)&h[(size_t)s * DD + lane * 2];
            a0x += v.x; a0y += v.y;
        }
    }
    float rd = 1.0f / fmaxf((float)(i1 - i0), 1.0f);
    ushort2 o;
    o.x = f2bs((a0x + a1x + a2x + a3x) * rd);
    o.y = f2bs((a0y + a1y + a2y + a3y) * rd);
    *(ushort2*)&out[(size_t)(d - lo) * DD + lane * 2] = o;
}

// ---- MFMA GEMM: out(bf16)[lo+r] = concat(A1[g(lo+r)], A2[r]) @ W + bias ----
#define ALD 264   // LDS row stride in bf16 (256 + 8 pad)
__global__ __launch_bounds__(256) void mfma_gemm(
    const void* __restrict__ A1v, const int* __restrict__ flagp,
    const int* __restrict__ gather, int lo,
    const unsigned short* __restrict__ A2,
    const uint4* __restrict__ wfrag, const float* __restrict__ bias,
    unsigned short* __restrict__ out, int Mc, int relu)
{
    __shared__ unsigned short As[64 * ALD];
    const int tid = threadIdx.x;
    const int rb = blockIdx.x * 64;
    const int abf = flagp ? *flagp : 1;
    const int KS = A2 ? 8 : 4;

    { // stage A: thread covers row = tid>>2, 32 cols at (tid&3)*32
        int r = tid >> 2, cs = (tid & 3) * 32;
        int gr = rb + r;
        unsigned short* dst = &As[r * ALD + cs];
        if (gr < Mc) {
            int ar = gather ? gather[lo + gr] : (lo + gr);
            if (abf) {
                const uint4* s = (const uint4*)((const unsigned short*)A1v + (size_t)ar * DD + cs);
                uint4* dv = (uint4*)dst;
#pragma unroll
                for (int i = 0; i < 4; ++i) dv[i] = s[i];
            } else {
                const float* s = (const float*)A1v + (size_t)ar * DD + cs;
#pragma unroll
                for (int i = 0; i < 32; ++i) dst[i] = f2bs(s[i]);
            }
            if (A2) {
                const uint4* s2 = (const uint4*)(A2 + (size_t)gr * DD + cs);
                uint4* d2 = (uint4*)(dst + 128);
#pragma unroll
                for (int i = 0; i < 4; ++i) d2[i] = s2[i];
            }
        } else {
            uint4 z = {0, 0, 0, 0};
            uint4* dv = (uint4*)dst;
#pragma unroll
            for (int i = 0; i < 4; ++i) dv[i] = z;
            if (A2) {
                uint4* d2 = (uint4*)(dst + 128);
#pragma unroll
                for (int i = 0; i < 4; ++i) d2[i] = z;
            }
        }
    }
    __syncthreads();

    const int w = tid >> 6, lane = tid & 63;
    const int m0 = w * 16;
    f32x4 acc[8] = {};

    for (int ks = 0; ks < KS; ++ks) {
        short8 a = *(const short8*)&As[(m0 + (lane & 15)) * ALD + ks * 32 + ((lane >> 4) & 3) * 8];
#pragma unroll
        for (int ct = 0; ct < 8; ++ct) {
            uint4 braw = wfrag[(ct * KS + ks) * 64 + lane];
            short8 b = *(short8*)&braw;
            acc[ct] = __builtin_amdgcn_mfma_f32_16x16x32_bf16(a, b, acc[ct], 0, 0, 0);
        }
    }

#pragma unroll
    for (int ct = 0; ct < 8; ++ct) {
        int col = ct * 16 + (lane & 15);
        float bv = bias[col];
#pragma unroll
        for (int r = 0; r < 4; ++r) {
            int grow = rb + m0 + ((lane >> 4) & 3) * 4 + r;
            if (grow >= Mc) continue;
            float v = acc[ct][r] + bv;
            if (relu) v = fmaxf(v, 0.0f);
            out[(size_t)(lo + grow) * DD + col] = f2bs(v);
        }
    }
}

// ---- column stats stage 1 (bf16 input) ----
__global__ __launch_bounds__(256) void colstats_p1(
    const unsigned short* __restrict__ t, int M,
    float* __restrict__ PS, float* __restrict__ PQ)
{
    __shared__ float sm[256], sq2[256];
    int tid = threadIdx.x;
    int c = tid & 127, h = tid >> 7;
    int rpb = (M + NBLK - 1) / NBLK;
    int r0 = blockIdx.x * rpb;
    int r1 = min(r0 + rpb, M);
    float s = 0.0f, ss = 0.0f;
    for (int r = r0 + h; r < r1; r += 2) {
        float v = b2f(t[(size_t)r * DD + c]);
        s += v; ss += v * v;
    }
    sm[tid] = s; sq2[tid] = ss;
    __syncthreads();
    if (tid < 128) {
        PS[blockIdx.x * 128 + tid] = sm[tid] + sm[tid + 128];
        PQ[blockIdx.x * 128 + tid] = sq2[tid] + sq2[tid + 128];
    }
}

// ---- column stats stage 2 ----
__global__ void colstats_p2(const float* __restrict__ PS, const float* __restrict__ PQ,
                            float* __restrict__ sum, float* __restrict__ sumsq) {
    int t = threadIdx.x;  // 256
    float a = 0.0f;
    if (t < 128) {
        for (int b = 0; b < NBLK; ++b) a += PS[b * 128 + t];
        sum[t] = a;
    } else {
        int c = t - 128;
        for (int b = 0; b < NBLK; ++b) a += PQ[b * 128 + c];
        sumsq[c] = a;
    }
}

// ---- BN + ReLU, in place on bf16, 4 elems/thread ----
__global__ __launch_bounds__(256) void bn_relu(
    unsigned short* __restrict__ h, int M, const float* __restrict__ sum,
    const float* __restrict__ sumsq,
    const float* __restrict__ gamma, const float* __restrict__ beta) {
    size_t i4 = (size_t)blockIdx.x * blockDim.x + threadIdx.x;
    size_t n4 = (size_t)M * 32;
    if (i4 >= n4) return;
    int c = (i4 & 31) * 4;
    ushort4 u = ((ushort4*)h)[i4];
    float x0 = b2f(u.x), x1 = b2f(u.y), x2 = b2f(u.z), x3 = b2f(u.w);
    float m[4], inv[4], g[4], be[4];
#pragma unroll
    for (int j = 0; j < 4; ++j) {
        m[j] = sum[c + j] / (float)M;
        float var = fmaxf(sumsq[c + j] / (float)M - m[j] * m[j], 0.0f);
        inv[j] = rsqrtf(var + BN_EPS);
        g[j] = gamma[c + j]; be[j] = beta[c + j];
    }
    u.x = f2bs(fmaxf(g[0] * (x0 - m[0]) * inv[0] + be[0], 0.0f));
    u.y = f2bs(fmaxf(g[1] * (x1 - m[1]) * inv[1] + be[1], 0.0f));
    u.z = f2bs(fmaxf(g[2] * (x2 - m[2]) * inv[2] + be[2], 0.0f));
    u.w = f2bs(fmaxf(g[3] * (x3 - m[3]) * inv[3] + be[3], 0.0f));
    ((ushort4*)h)[i4] = u;
}

// ---- summary -> wsvec ----
__global__ void make_ws(const float* __restrict__ colsum, const float* __restrict__ discW,
                        float* __restrict__ wsv, int M) {
    __shared__ float s[128];
    int t = threadIdx.x;  // 128
    s[t] = 1.0f / (1.0f + expf(-(colsum[t] / (float)M)));
    __syncthreads();
    float acc = 0.0f;
    for (int j = 0; j < 128; ++j) acc += discW[t * 128 + j] * s[j];
    wsv[t] = acc;
}

// ---- loss stage 1 (bf16 inputs) ----
__global__ __launch_bounds__(256) void loss_partial(
    const unsigned short* __restrict__ P, const unsigned short* __restrict__ Ng,
    const float* __restrict__ wsv, float* __restrict__ lossP, float* __restrict__ lossN, int M)
{
    __shared__ float sP[4], sN[4];
    int lane = threadIdx.x & 63;
    int wave = threadIdx.x >> 6;
    int gw = blockIdx.x * 4 + wave;
    int nw = gridDim.x * 4;
    float w0 = wsv[lane], w1 = wsv[lane + 64];
    float accP = 0.0f, accN = 0.0f;
    for (int row = gw; row < 2 * M; row += nw) {
        const unsigned short* base = (row < M) ? &P[(size_t)row * DD]
                                               : &Ng[(size_t)(row - M) * DD];
        float a = b2f(base[lane]) * w0 + b2f(base[lane + 64]) * w1;
#pragma unroll
        for (int off = 32; off > 0; off >>= 1) a += __shfl_down(a, off, 64);
        if (lane == 0) {
            float x = (row < M) ? -a : a;
            float sp = fmaxf(x, 0.0f) + log1pf(expf(-fabsf(x)));
            if (row < M) accP += sp; else accN += sp;
        }
    }
    if (lane == 0) { sP[wave] = accP; sN[wave] = accN; }
    __syncthreads();
    if (threadIdx.x == 0) {
        lossP[blockIdx.x] = sP[0] + sP[1] + sP[2] + sP[3];
        lossN[blockIdx.x] = sN[0] + sN[1] + sN[2] + sN[3];
    }
}

// ---- loss stage 2 ----
__global__ void write_loss(const float* __restrict__ lossP, const float* __restrict__ lossN,
                           void* __restrict__ outv, int M, const int* __restrict__ flagp) {
    __shared__ float s[256];
    int t = threadIdx.x;  // 256
    s[t] = (t < NBLK) ? (lossP[t] + lossN[t]) : 0.0f;
    __syncthreads();
    for (int off = 128; off > 0; off >>= 1) { if (t < off) s[t] += s[t + off]; __syncthreads(); }
    if (t == 0) {
        float v = s[0] / (float)M;
        if (*flagp) ((bf16*)outv)[20000] = __float2bfloat16(v);
        else        ((float*)outv)[20000] = v;
    }
}

// ---- predictor input (bf16 in/out) ----
__global__ __launch_bounds__(256) void pair_mult(
    const unsigned short* __restrict__ P, const int* __restrict__ s_idx,
    const int* __restrict__ d_idx, unsigned short* __restrict__ Z, int nPair) {
    int i = blockIdx.x * 2 + (threadIdx.x >> 7);
    int f = threadIdx.x & 127;
    if (i >= nPair) return;
    float v = b2f(P[(size_t)s_idx[i] * DD + f]) * b2f(P[(size_t)d_idx[i] * DD + f]);
    Z[(size_t)i * DD + f] = f2bs(v);
}

// ---- final 128 -> 1 matvec (bf16 input) ----
__global__ __launch_bounds__(256) void final_mv(
    const unsigned short* __restrict__ ZB, const float* __restrict__ pW3,
    const float* __restrict__ pb3,
    void* __restrict__ outv, int nRows, int outOff, const int* __restrict__ flagp) {
    int row = blockIdx.x * 4 + (threadIdx.x >> 6);
    int lane = threadIdx.x & 63;
    if (row >= nRows) return;
    float a = b2f(ZB[(size_t)row * DD + lane]) * pW3[lane]
            + b2f(ZB[(size_t)row * DD + lane + 64]) * pW3[lane + 64];
#pragma unroll
    for (int off = 32; off > 0; off >>= 1) a += __shfl_down(a, off, 64);
    if (lane == 0) {
        float v = a + pb3[0];
        if (*flagp) ((bf16*)outv)[outOff + row] = __float2bfloat16(v);
        else        ((float*)outv)[outOff + row] = v;
    }
}

extern "C" void kernel_launch(void* const* d_in, const int* in_sizes, int n_in,
                              void* d_out, int out_size, void* d_ws, size_t ws_size,
                              hipStream_t stream)
{
    const void* x      = d_in[0];
    const int* srcA[3] = {(const int*)d_in[1], (const int*)d_in[3], (const int*)d_in[5]};
    const int* dstA[3] = {(const int*)d_in[2], (const int*)d_in[4], (const int*)d_in[6]};
    const int* perm    = (const int*)d_in[7];
    const int* pos_src = (const int*)d_in[8];
    const int* pos_dst = (const int*)d_in[9];
    const int* neg_src = (const int*)d_in[10];
    const int* neg_dst = (const int*)d_in[11];

    const int N1 = 50000, N2 = 25000, N3 = 12500;
    const int E[3] = {750000, 250000, 125000};
    const int EP = 10000;
    const int NCAT = 87500;                       // concatenated dst rows

    // ---- ws layout (4-byte units), peak ~45 MiB ----
    float* wsf = (float*)d_ws;
    int*   wsi = (int*)d_ws;
    int*   flagp = wsi;
    float* PS    = wsf + 256;                     // 20480
    float* PQ    = wsf + 20736;                   // 20480
    float* lossP = wsf + 41216;                   // 160
    float* lossN = wsf + 41376;                   // 160
    float* sumS  = wsf + 41600;                   // 128
    float* sqS   = wsf + 41728;                   // 128
    float* wsvec = wsf + 41856;                   // 128
    int*   bsums = wsi + 41984;                   // 256
    int* histAll = wsi + 43008;                   // 87500
    int* curAll  = wsi + 130560;                  // 87500 (ends 218060)
    unsigned short* wfragL[3] = {(unsigned short*)(wsi + 218112),
                                 (unsigned short*)(wsi + 234496),
                                 (unsigned short*)(wsi + 250880)};   // 16384 fl each
    unsigned short* wfragP[2] = {(unsigned short*)(wsi + 267264),
                                 (unsigned short*)(wsi + 275456)};   // 8192 fl each
    int* rpAll  = wsi + 283648;                   // 87501
    int* eidAll = wsi + 371200;                   // 1,125,000 (ends 1,496,200)
    const size_t WfB = 1496320;
    float* WS[3] = {wsf + WfB +      0, wsf + WfB +  32896, wsf + WfB +  65792};
    float* WN[3] = {wsf + WfB +  16384, wsf + WfB +  49280, wsf + WfB +  82176};
    float* BV[3] = {wsf + WfB +  32768, wsf + WfB +  65664, wsf + WfB +  98560};
    float* G0  = wsf + WfB +  98688; float* BE0 = wsf + WfB +  98816;
    float* G1  = wsf + WfB +  98944; float* BE1 = wsf + WfB +  99072;
    float* DW  = wsf + WfB +  99200;
    float* PW1 = wsf + WfB + 115584; float* PB1 = wsf + WfB + 131968;
    float* PW2 = wsf + WfB + 132096; float* PB2 = wsf + WfB + 148480;
    float* PW3 = wsf + WfB + 148608; float* PB3 = wsf + WfB + 148736;
    unsigned short* PF  = (unsigned short*)(wsf + 1645312);   //  800000 fl
    unsigned short* NF  = (unsigned short*)(wsf + 2445312);   //  800000 fl
    unsigned short* H2  = (unsigned short*)(wsf + 3245312);   // 1600000 fl
    unsigned short* H1  = (unsigned short*)(wsf + 4845312);   // 3200000 fl
    unsigned short* AGG = (unsigned short*)(wsf + 8045312);   // 3200000 fl (-> 11245312)
    // predictor overlays in dead H1 (bf16, 640000 fl each):
    unsigned short* Z  = H1;
    unsigned short* ZA = (unsigned short*)(wsf + 4845312 + 640000);
    unsigned short* ZB = (unsigned short*)(wsf + 4845312 + 1280000);

    // ---- dtype detect + fused weight conversion ----
    detect_dtype<<<1, 256, 0, stream>>>((const unsigned int*)x, flagp);
    CvtTable tab;
    const int widx[20] = {12,13,14, 15,16,17, 18,19,20, 21,22,23,24, 25, 26,27, 28,29, 30,31};
    float* wdst[20] = {WS[0],WN[0],BV[0], WS[1],WN[1],BV[1], WS[2],WN[2],BV[2],
                       G0,BE0,G1,BE1, DW, PW1,PB1, PW2,PB2, PW3,PB3};
    const int wn[20] = {16384,16384,128, 16384,16384,128, 16384,16384,128,
                        128,128,128,128, 16384, 16384,128, 16384,128, 128,1};
    int tot = 0;
    for (int k = 0; k < 20; ++k) {
        tab.src[k] = d_in[widx[k]];
        tab.off[k] = (int)(wdst[k] - wsf);
        tab.n[k] = wn[k];
        tot += wn[k];
    }
    tab.total = tot;
    cvt_all<<<(tot + 255) / 256, 256, 0, stream>>>(tab, wsf, flagp);

    // ---- CSR build (concatenated, windowed) ----
    hipMemsetAsync(histAll, 0, (size_t)(2 * NCAT + 64) * 4, stream);  // hist + cur
    hist_win<<<512, 256, 0, stream>>>(dstA[0], E[0], dstA[1], E[1], dstA[2], E[2], histAll);
    {
        int nb = (NCAT / 4 + 255) / 256;   // 86
        scan_bsum<<<nb, 256, 0, stream>>>(histAll, NCAT, bsums);
        scan_bscan<<<1, 256, 0, stream>>>(bsums, nb, rpAll + NCAT);
        scan_apply<<<nb, 256, 0, stream>>>(histAll, NCAT, bsums, rpAll);
    }
    csr_fill_win<<<512, 256, 0, stream>>>(
        srcA[0], dstA[0], E[0], srcA[1], dstA[1], E[1], srcA[2], dstA[2], E[2],
        rpAll, curAll, eidAll);

    // ---- MFMA W-fragment tables (one fused launch) ----
    WfAll wa;
    wa.W1[0] = WS[0]; wa.W2[0] = WN[0]; wa.dst[0] = wfragL[0]; wa.KS[0] = 8; wa.start[0] = 0;
    wa.W1[1] = WS[1]; wa.W2[1] = WN[1]; wa.dst[1] = wfragL[1]; wa.KS[1] = 8; wa.start[1] = 4096;
    wa.W1[2] = WS[2]; wa.W2[2] = WN[2]; wa.dst[2] = wfragL[2]; wa.KS[2] = 8; wa.start[2] = 8192;
    wa.W1[3] = PW1;   wa.W2[3] = nullptr; wa.dst[3] = wfragP[0]; wa.KS[3] = 4; wa.start[3] = 12288;
    wa.W1[4] = PW2;   wa.W2[4] = nullptr; wa.dst[4] = wfragP[1]; wa.KS[4] = 4; wa.start[4] = 14336;
    wa.total = 16384;
    wfrag_all<<<64, 256, 0, stream>>>(wa);

    for (int pass = 0; pass < 2; ++pass) {
        const int* g = (pass == 0) ? nullptr : perm;
        unsigned short* OUT = (pass == 0) ? PF : NF;

        // ===== layer 0 (M=50000), single chunk =====
        gather_mean<<<(N1 + 3) / 4, 256, 0, stream>>>(
            x, flagp, g, rpAll + 0, eidAll, 0, N1, AGG);
        mfma_gemm<<<(N1 + 63) / 64, 256, 0, stream>>>(
            x, flagp, g, 0, AGG, (const uint4*)wfragL[0], BV[0], H1, N1, 0);
        colstats_p1<<<NBLK, 256, 0, stream>>>(H1, N1, PS, PQ);
        colstats_p2<<<1, 256, 0, stream>>>(PS, PQ, sumS, sqS);
        bn_relu<<<((size_t)N1 * 32 + 255) / 256, 256, 0, stream>>>(H1, N1, sumS, sqS, G0, BE0);

        // ===== layer 1 (M=25000) =====
        gather_mean<<<(N2 + 3) / 4, 256, 0, stream>>>(
            H1, nullptr, nullptr, rpAll + 50000, eidAll, 0, N2, AGG);
        mfma_gemm<<<(N2 + 63) / 64, 256, 0, stream>>>(
            H1, nullptr, nullptr, 0, AGG, (const uint4*)wfragL[1], BV[1], H2, N2, 0);
        colstats_p1<<<NBLK, 256, 0, stream>>>(H2, N2, PS, PQ);
        colstats_p2<<<1, 256, 0, stream>>>(PS, PQ, sumS, sqS);
        bn_relu<<<((size_t)N2 * 32 + 255) / 256, 256, 0, stream>>>(H2, N2, sumS, sqS, G1, BE1);

        // ===== layer 2 (M=12500), no BN =====
        gather_mean<<<(N3 + 3) / 4, 256, 0, stream>>>(
            H2, nullptr, nullptr, rpAll + 75000, eidAll, 0, N3, AGG);
        mfma_gemm<<<(N3 + 63) / 64, 256, 0, stream>>>(
            H2, nullptr, nullptr, 0, AGG, (const uint4*)wfragL[2], BV[2], OUT, N3, 0);
    }

    // ---- summary / discriminator loss ----
    colstats_p1<<<NBLK, 256, 0, stream>>>(PF, N3, PS, PQ);
    colstats_p2<<<1, 256, 0, stream>>>(PS, PQ, sumS, sqS);
    make_ws<<<1, 128, 0, stream>>>(sumS, DW, wsvec, N3);
    loss_partial<<<NBLK, 256, 0, stream>>>(PF, NF, wsvec, lossP, lossN, N3);
    write_loss<<<1, 256, 0, stream>>>(lossP, lossN, d_out, N3, flagp);

    // ---- predictor MLP: pos pairs then neg pairs ----
    for (int c = 0; c < 2; ++c) {
        const int* si = (c == 0) ? pos_src : neg_src;
        const int* di = (c == 0) ? pos_dst : neg_dst;
        pair_mult<<<(EP + 1) / 2, 256, 0, stream>>>(PF, si, di, Z, EP);
        mfma_gemm<<<(EP + 63) / 64, 256, 0, stream>>>(
            Z, nullptr, nullptr, 0, nullptr, (const uint4*)wfragP[0], PB1, ZA, EP, 1);
        mfma_gemm<<<(EP + 63) / 64, 256, 0, stream>>>(
            ZA, nullptr, nullptr, 0, nullptr, (const uint4*)wfragP[1], PB2, ZB, EP, 1);
        final_mv<<<(EP + 3) / 4, 256, 0, stream>>>(ZB, PW3, PB3, d_out, EP, c * EP, flagp);
    }
}